// Round 18
// baseline (471.796 us; speedup 1.0000x reference)
//
#include <hip/hip_runtime.h>
#include <cstdint>
#include <cstddef>

#define BN_EPS 1e-5f
#define NSLICE 128
#define BK_BITS 7
#define BK_SIZE 128
#define NBK_MAX 1024
#define EB_CAP 5120

typedef __attribute__((ext_vector_type(8))) __bf16 bf16x8;
typedef __attribute__((ext_vector_type(4))) float f32x4;
typedef __attribute__((ext_vector_type(2))) float f32x2;

// ---------------- helpers ----------------

__device__ inline uint16_t f2bf(float f){
  union {float f; uint32_t u;} v; v.f = f;
  uint32_t u = v.u;
  return (uint16_t)((u + 0x7FFFu + ((u >> 16) & 1u)) >> 16);
}

__device__ inline uint32_t pack2bf(float a, float b){
  return (uint32_t)f2bf(a) | ((uint32_t)f2bf(b) << 16);
}

__device__ inline void bf2f2(uint32_t w, float& a, float& b){
  union {uint32_t u; float f;} ua, ub;
  ua.u = w << 16; ub.u = w & 0xFFFF0000u;
  a = ua.f; b = ub.f;
}

__device__ inline uint8_t f2fp8(float v){
  uint32_t t = (uint32_t)__builtin_amdgcn_cvt_pk_fp8_f32(v, v, 0, false);
  return (uint8_t)(t & 0xFF);
}

__device__ inline void prepW_body(const float* W, uint16_t* WTf, int K, int NOUT, int id){
  if (id >= K*NOUT) return;
  int j    = id & 7;
  int l    = (id >> 3) & 63;
  int l15  = l & 15, quad = l >> 4;
  int rest = id >> 9;
  int KS   = K >> 5;
  int ks   = rest % KS;
  int t    = rest / KS;
  int k = ks*32 + quad*8 + j;
  int n = t*16 + l15;
  WTf[id] = f2bf(W[(size_t)k*NOUT + n]);
}

// ---------------- fused init ----------------
__global__ __launch_bounds__(256) void k_misc(
    const int* __restrict__ batch, int* __restrict__ gstart, int N, int G, int cbN,
    const float* __restrict__ W1, uint16_t* __restrict__ WT1,
    const float* __restrict__ W2, uint16_t* __restrict__ WT2,
    int* __restrict__ bcur,
    float4* __restrict__ gstats4, float4* __restrict__ embsum4)
{
  int b = blockIdx.x;
  int t = threadIdx.x;
  float4 z4 = {0.f,0.f,0.f,0.f};
  if (b < 256){
    gstats4[b*256 + t] = z4;
  } else if (b < 1280){
    embsum4[(b-256)*256 + t] = z4;
  } else if (b < 1280 + cbN){
    int i = (b-1280)*256 + t;
    if (i < N){
      int bb = batch[i];
      int bp = (i > 0) ? batch[i-1] : -1;
      for (int g = bp+1; g <= bb; g++) gstart[g] = i;
      if (i == N-1){
        for (int g = bb+1; g <= G; g++) gstart[g] = N;
      }
    }
  } else if (b == 1280 + cbN){
    for (int i = t; i < NBK_MAX; i += 256) bcur[i] = i * EB_CAP;
  } else if (b < 1280 + cbN + 1 + 32){
    prepW_body(W1, WT1, 64, 128, (b - 1280 - cbN - 1)*256 + t);
  } else {
    prepW_body(W2, WT2, 128, 256, (b - 1280 - cbN - 33)*256 + t);
  }
}

// ---------------- graph preprocessing: 128-node buckets ----------------
#define PA_TILE 8192

// two-phase: histogram over 8192-edge tile, reserve, re-read+scatter (longer runs)
__global__ __launch_bounds__(256) void k_passA(
    const int* __restrict__ row, const int* __restrict__ col,
    int* __restrict__ bcur, uint32_t* __restrict__ ebuf, int E)
{
  __shared__ int hist[NBK_MAX];
  __shared__ int rbase[NBK_MAX];
  int t = threadIdx.x;
  int start = blockIdx.x * PA_TILE;
  for (int i = t; i < NBK_MAX; i += 256) hist[i] = 0;
  __syncthreads();
  // phase 1: histogram
  #pragma unroll
  for (int rr = 0; rr < 2; rr++){
    #pragma unroll
    for (int j = 0; j < 16; j++){
      int e = start + rr*4096 + t + j*256;
      if (e < E) atomicAdd(&hist[col[e] >> BK_BITS], 1);
    }
  }
  __syncthreads();
  for (int i = t; i < NBK_MAX; i += 256){
    int h = hist[i];
    rbase[i] = (h > 0) ? atomicAdd(&bcur[i], h) : 0;
  }
  __syncthreads();
  for (int i = t; i < NBK_MAX; i += 256) hist[i] = 0;
  __syncthreads();
  // phase 2: scatter (re-read; L2-hot)
  #pragma unroll
  for (int rr = 0; rr < 2; rr++){
    #pragma unroll
    for (int j = 0; j < 16; j++){
      int e = start + rr*4096 + t + j*256;
      if (e < E){
        int r = row[e], c = col[e];
        int bb = c >> BK_BITS;
        int pos = rbase[bb] + atomicAdd(&hist[bb], 1);
        ebuf[pos] = ((uint32_t)r << BK_BITS) | (uint32_t)(c & (BK_SIZE-1));
      }
    }
  }
}

__global__ __launch_bounds__(256) void k_bscan(const int* __restrict__ bcur,
                                               int* __restrict__ bbase, int E, int nb){
  __shared__ int s[256];
  int t = threadIdx.x;
  int base = t*4;
  int v0 = (base+0 < nb) ? (bcur[base+0] - (base+0)*EB_CAP) : 0;
  int v1 = (base+1 < nb) ? (bcur[base+1] - (base+1)*EB_CAP) : 0;
  int v2 = (base+2 < nb) ? (bcur[base+2] - (base+2)*EB_CAP) : 0;
  int v3 = (base+3 < nb) ? (bcur[base+3] - (base+3)*EB_CAP) : 0;
  int lsum = v0+v1+v2+v3;
  s[t] = lsum;
  __syncthreads();
  for (int off=1; off<256; off<<=1){
    int x = 0;
    if (t >= off) x = s[t-off];
    __syncthreads();
    if (t >= off) s[t] += x;
    __syncthreads();
  }
  int excl = s[t] - lsum;
  bbase[base+0] = excl;
  bbase[base+1] = excl + v0;
  bbase[base+2] = excl + v0 + v1;
  bbase[base+3] = excl + v0 + v1 + v2;
  if (t == 255) bbase[1024] = E;
}

// passB2 (128-node buckets) + fused x->xs conversion
__global__ __launch_bounds__(256) void k_passB2(
    const uint32_t* __restrict__ ebuf, const int* __restrict__ bbase,
    int* __restrict__ offs, float* __restrict__ dinv,
    int* __restrict__ csr,
    const float4* __restrict__ x, ushort4* __restrict__ xs,
    int N, int E, int nb)
{
  __shared__ int deg[BK_SIZE];
  __shared__ int cur[BK_SIZE];
  __shared__ int ps[BK_SIZE];
  int b = blockIdx.x;
  int base = b << BK_BITS;
  int t = threadIdx.x;
  int s = bbase[b], e = bbase[b+1];
  int ecnt = e - s;
  const uint32_t* eb = ebuf + (size_t)b*EB_CAP;
  if (t < BK_SIZE) deg[t] = 0;
  __syncthreads();
  for (int i = t; i < ecnt; i += 256)
    atomicAdd(&deg[eb[i] & (BK_SIZE-1u)], 1);
  __syncthreads();
  int d = (t < BK_SIZE) ? deg[t] : 0;
  if (t < BK_SIZE) ps[t] = d;
  __syncthreads();
  for (int off=1; off<BK_SIZE; off<<=1){
    int x_ = 0;
    if (t < BK_SIZE && t >= off) x_ = ps[t-off];
    __syncthreads();
    if (t < BK_SIZE && t >= off) ps[t] += x_;
    __syncthreads();
  }
  if (t < BK_SIZE){
    int o = s + ps[t] - d;
    cur[t] = o;
    int n0 = base + t;
    if (n0 < N){ offs[n0] = o; dinv[n0] = 1.0f / sqrtf((float)(d + 1)); }
  }
  if (b == nb-1 && t == 0) offs[N] = E;
  __syncthreads();
  for (int i = t; i < ecnt; i += 256){
    uint32_t v = eb[i];
    int local = v & (BK_SIZE-1u);
    int pos = atomicAdd(&cur[local], 1);
    csr[pos] = (int)(v >> BK_BITS);
  }
  for (int idx = t; idx < BK_SIZE*16; idx += 256){
    int local = idx >> 4;
    int node = base + local;
    if (node < N){
      float dd = 1.0f / sqrtf((float)(deg[local] + 1));
      int c16 = idx & 15;
      float4 v = x[(size_t)node*16 + c16];
      ushort4 o;
      o.x = f2bf(v.x*dd); o.y = f2bf(v.y*dd); o.z = f2bf(v.z*dd); o.w = f2bf(v.w*dd);
      xs[(size_t)node*16 + c16] = o;
    }
  }
}

// parallel bn finalize: one block per column, slice-parallel tree reduce
__global__ __launch_bounds__(128) void k_bnfin(const float* __restrict__ region, int F, float invCount,
                        const float* __restrict__ g, const float* __restrict__ be,
                        float* __restrict__ scale, float* __restrict__ shift){
  __shared__ float ss[128], sq[128];
  int i  = blockIdx.x;
  int sl = threadIdx.x;
  ss[sl] = region[sl*2*F + i];
  sq[sl] = region[sl*2*F + F + i];
  __syncthreads();
  for (int off = 64; off > 0; off >>= 1){
    if (sl < off){ ss[sl] += ss[sl+off]; sq[sl] += sq[sl+off]; }
    __syncthreads();
  }
  if (sl == 0){
    float mu  = ss[0] * invCount;
    float var = sq[0] * invCount - mu*mu;
    if (var < 0.f) var = 0.f;
    float rstd = 1.0f / sqrtf(var + BN_EPS);
    float sc = g[i] * rstd;
    scale[i] = sc;
    shift[i] = be[i] - mu * sc;
  }
}

// ---------------- aggregation kernels ----------------
__global__ __launch_bounds__(256) void k_agg1(
    const uint4* __restrict__ xs, const int* __restrict__ offs, const int* __restrict__ csr,
    const float* __restrict__ dinv, uint4* __restrict__ z, float* __restrict__ dsum, int N)
{
  int sub = threadIdx.x >> 3, lane = threadIdx.x & 7;
  int node = blockIdx.x*32 + sub;
  if (node >= N) return;
  int s = offs[node], e = offs[node+1];
  float acc[8] = {};
  float ds = 0.f;
  auto add8 = [&](uint4 v){
    float f0,f1,f2,f3,f4,f5,f6,f7;
    bf2f2(v.x, f0, f1); bf2f2(v.y, f2, f3);
    bf2f2(v.z, f4, f5); bf2f2(v.w, f6, f7);
    acc[0]+=f0; acc[1]+=f1; acc[2]+=f2; acc[3]+=f3;
    acc[4]+=f4; acc[5]+=f5; acc[6]+=f6; acc[7]+=f7;
  };
  int i = s;
  for (; i + 4 <= e; i += 4){
    int r0 = csr[i], r1 = csr[i+1], r2 = csr[i+2], r3 = csr[i+3];
    uint4 v0 = xs[r0*8 + lane];
    uint4 v1 = xs[r1*8 + lane];
    uint4 v2 = xs[r2*8 + lane];
    uint4 v3 = xs[r3*8 + lane];
    add8(v0); add8(v1); add8(v2); add8(v3);
    if (lane == 0) ds += dinv[r0] + dinv[r1] + dinv[r2] + dinv[r3];
  }
  for (; i < e; i++){
    int r0 = csr[i];
    add8(xs[r0*8 + lane]);
    if (lane == 0) ds += dinv[r0];
  }
  add8(xs[node*8 + lane]);
  float d = dinv[node];
  if (lane == 0) dsum[node] = ds + d;
  uint4 o;
  o.x = pack2bf(acc[0]*d, acc[1]*d);
  o.y = pack2bf(acc[2]*d, acc[3]*d);
  o.z = pack2bf(acc[4]*d, acc[5]*d);
  o.w = pack2bf(acc[6]*d, acc[7]*d);
  z[(node>>4)*128 + lane*16 + (node&15)] = o;
}

// agg2: gather u (fp8, 16B/lane, 8 lanes/node) -> algebraic bn1 affine -> z2
__global__ __launch_bounds__(256) void k_agg2(
    const uint4* __restrict__ u, const int* __restrict__ offs, const int* __restrict__ csr,
    const float* __restrict__ dinv, const float* __restrict__ dsum,
    const float* __restrict__ sc1, const float* __restrict__ sh1,
    uint4* __restrict__ z, int N)
{
  int sub = threadIdx.x >> 3, lane = threadIdx.x & 7;
  int node = blockIdx.x*32 + sub;
  if (node >= N) return;
  int s = offs[node], e = offs[node+1];
  float acc[16] = {};
  auto add16 = [&](uint4 v){
    f32x2 p;
    p = __builtin_amdgcn_cvt_pk_f32_fp8((int)v.x, false); acc[0]+=p.x;  acc[1]+=p.y;
    p = __builtin_amdgcn_cvt_pk_f32_fp8((int)v.x, true ); acc[2]+=p.x;  acc[3]+=p.y;
    p = __builtin_amdgcn_cvt_pk_f32_fp8((int)v.y, false); acc[4]+=p.x;  acc[5]+=p.y;
    p = __builtin_amdgcn_cvt_pk_f32_fp8((int)v.y, true ); acc[6]+=p.x;  acc[7]+=p.y;
    p = __builtin_amdgcn_cvt_pk_f32_fp8((int)v.z, false); acc[8]+=p.x;  acc[9]+=p.y;
    p = __builtin_amdgcn_cvt_pk_f32_fp8((int)v.z, true ); acc[10]+=p.x; acc[11]+=p.y;
    p = __builtin_amdgcn_cvt_pk_f32_fp8((int)v.w, false); acc[12]+=p.x; acc[13]+=p.y;
    p = __builtin_amdgcn_cvt_pk_f32_fp8((int)v.w, true ); acc[14]+=p.x; acc[15]+=p.y;
  };
  int i = s;
  for (; i + 4 <= e; i += 4){
    int r0 = csr[i], r1 = csr[i+1], r2 = csr[i+2], r3 = csr[i+3];
    uint4 v0 = u[r0*8 + lane];
    uint4 v1 = u[r1*8 + lane];
    uint4 v2 = u[r2*8 + lane];
    uint4 v3 = u[r3*8 + lane];
    add16(v0); add16(v1); add16(v2); add16(v3);
  }
  for (; i < e; i++) add16(u[csr[i]*8 + lane]);
  add16(u[node*8 + lane]);
  float d  = dinv[node];
  float ds = dsum[node];
  int f0 = lane*16;
  uint4 o0, o1;
  {
    float4 sa = *(const float4*)(sc1 + f0);
    float4 sb = *(const float4*)(sc1 + f0 + 4);
    float4 ha = *(const float4*)(sh1 + f0);
    float4 hb = *(const float4*)(sh1 + f0 + 4);
    o0.x = pack2bf(d*fmaf(sa.x, acc[0], ha.x*ds), d*fmaf(sa.y, acc[1], ha.y*ds));
    o0.y = pack2bf(d*fmaf(sa.z, acc[2], ha.z*ds), d*fmaf(sa.w, acc[3], ha.w*ds));
    o0.z = pack2bf(d*fmaf(sb.x, acc[4], hb.x*ds), d*fmaf(sb.y, acc[5], hb.y*ds));
    o0.w = pack2bf(d*fmaf(sb.z, acc[6], hb.z*ds), d*fmaf(sb.w, acc[7], hb.w*ds));
  }
  {
    float4 sa = *(const float4*)(sc1 + f0 + 8);
    float4 sb = *(const float4*)(sc1 + f0 + 12);
    float4 ha = *(const float4*)(sh1 + f0 + 8);
    float4 hb = *(const float4*)(sh1 + f0 + 12);
    o1.x = pack2bf(d*fmaf(sa.x, acc[8],  ha.x*ds), d*fmaf(sa.y, acc[9],  ha.y*ds));
    o1.y = pack2bf(d*fmaf(sa.z, acc[10], ha.z*ds), d*fmaf(sa.w, acc[11], ha.w*ds));
    o1.z = pack2bf(d*fmaf(sb.x, acc[12], hb.x*ds), d*fmaf(sb.y, acc[13], hb.y*ds));
    o1.w = pack2bf(d*fmaf(sb.z, acc[14], hb.z*ds), d*fmaf(sb.w, acc[15], hb.w*ds));
  }
  size_t zb = (size_t)(node>>4)*256 + (node&15);
  z[zb + (2*lane)*16]   = o0;
  z[zb + (2*lane+1)*16] = o1;
}

// ---------------- MFMA node GEMM ----------------
template<int K, int NOUT, bool POOL>
__global__ __launch_bounds__(256) void k_gemm_mfma(
    const uint16_t* __restrict__ A, const uint16_t* __restrict__ WTf,
    const float* __restrict__ bias, const int* __restrict__ batch,
    const float* __restrict__ dinv,
    uint8_t* __restrict__ u_out, float* __restrict__ embsum,
    float* __restrict__ gstats, int N)
{
  constexpr int NT = NOUT/16;
  constexpr int KS = K/32;
  constexpr int TRS8 = NOUT + 16;
  constexpr int TRSF = NOUT + 8;
  __shared__ float s_bias[NOUT];
  __shared__ int s_batch[64];
  __shared__ float s_dinv[POOL ? 1 : 64];
  __shared__ float s_sum[POOL ? 1 : NOUT];
  __shared__ float s_sq[POOL ? 1 : NOUT];
  __shared__ float s_trf[POOL ? 64*TRSF : 1];
  __shared__ uint8_t s_tr8[POOL ? 16 : 64*TRS8];
  int tid = threadIdx.x;
  int w = tid >> 6;
  int lane = tid & 63;
  int l15 = lane & 15, quad = lane >> 4;
  int m0 = blockIdx.x * 64;
  for (int i = tid; i < NOUT; i += 256) s_bias[i] = bias[i];
  if constexpr (!POOL){
    for (int i = tid; i < NOUT; i += 256){ s_sum[i]=0.f; s_sq[i]=0.f; }
    if (tid < 64) s_dinv[tid] = (m0+tid < N) ? dinv[m0+tid] : 0.f;
  }
  if (POOL && tid < 64) s_batch[tid] = (m0+tid < N) ? batch[m0+tid] : -1;
  __syncthreads();

  const uint16_t* Ag = A + (size_t)(m0/16 + w)*(16*K);

  f32x4 acc[NT];
  #pragma unroll
  for (int t=0;t<NT;t++) acc[t] = (f32x4){0.f,0.f,0.f,0.f};

  #pragma unroll
  for (int ks=0; ks<KS; ks++){
    bf16x8 af = *(const bf16x8*)(Ag + (ks*4 + quad)*128 + l15*8);
    #pragma unroll
    for (int t=0;t<NT;t++){
      bf16x8 bw = *(const bf16x8*)(WTf + (((size_t)(t*KS + ks)*64 + lane) << 3));
      acc[t] = __builtin_amdgcn_mfma_f32_16x16x32_bf16(af, bw, acc[t], 0, 0, 0);
    }
  }

  int rloc = w*16 + quad*4;
  if constexpr (POOL){
    #pragma unroll
    for (int t=0;t<NT;t++){
      int n = t*16 + l15;
      float bv = s_bias[n];
      #pragma unroll
      for (int r=0;r<4;r++){
        bool valid = (m0 + rloc + r) < N;
        float val = fmaxf(acc[t][r] + bv, 0.f);
        s_trf[(rloc + r)*TRSF + n] = valid ? val : 0.f;
      }
    }
    __syncthreads();
    {
      int n = tid;
      float vs = 0.f, vq = 0.f;
      int cur = -1; float run = 0.f;
      #pragma unroll 8
      for (int row = 0; row < 64; row++){
        float v = s_trf[row*TRSF + n];
        vs += v; vq += v*v;
        int b = s_batch[row];
        if (b != cur){
          if (cur >= 0 && run != 0.f) atomicAdd(&embsum[(size_t)cur*NOUT + n], run);
          cur = b; run = v;
        } else run += v;
      }
      if (cur >= 0 && run != 0.f) atomicAdd(&embsum[(size_t)cur*NOUT + n], run);
      float* gs = gstats + (size_t)(blockIdx.x & (NSLICE-1))*(2*NOUT);
      atomicAdd(&gs[n], vs);
      atomicAdd(&gs[NOUT + n], vq);
    }
  } else {
    #pragma unroll
    for (int t=0;t<NT;t++){
      int n = t*16 + l15;
      float bv = s_bias[n];
      float vs = 0.f, vq = 0.f;
      #pragma unroll
      for (int r=0;r<4;r++){
        bool valid = (m0 + rloc + r) < N;
        float val = fmaxf(acc[t][r] + bv, 0.f);
        float o = valid ? val : 0.f;
        vs += o; vq += o*o;
        s_tr8[(rloc + r)*TRS8 + n] = f2fp8(o * s_dinv[rloc + r]);
      }
      vs += __shfl_xor(vs, 16); vs += __shfl_xor(vs, 32);
      vq += __shfl_xor(vq, 16); vq += __shfl_xor(vq, 32);
      if (quad == 0){
        atomicAdd(&s_sum[n], vs);
        atomicAdd(&s_sq[n], vq);
      }
    }
    __syncthreads();
    constexpr int CPR = NOUT/16;
    for (int i = tid; i < 64*CPR; i += 256){
      int row = i / CPR, c = i - row*CPR;
      int grow = m0 + row;
      if (grow < N)
        *(uint4*)(u_out + (size_t)grow*NOUT + c*16) = *(const uint4*)(s_tr8 + row*TRS8 + c*16);
    }
    float* gs = gstats + (size_t)(blockIdx.x & (NSLICE-1))*(2*NOUT);
    for (int i = tid; i < NOUT; i += 256){
      atomicAdd(&gs[i], s_sum[i]);
      atomicAdd(&gs[NOUT + i], s_sq[i]);
    }
  }
}

// ---------------- GEMM (head MLP, fp32), 32-row x 64-col tiles ----------------
template<int K, int NWTOT, bool CONCAT, bool AFFINE, bool EMB>
__global__ __launch_bounds__(256) void k_gemm_mlp(
    const float* __restrict__ A0, const float* __restrict__ A1,
    const float* __restrict__ W,
    const float* __restrict__ scale, const float* __restrict__ shift,
    const int* __restrict__ gstart, const float* __restrict__ esc, const float* __restrict__ esh,
    const float* __restrict__ bias,
    float* __restrict__ out, float* __restrict__ gstats, int nrows)
{
  __shared__ float As[32*69];
  __shared__ float Bs[32*64];
  __shared__ float s_sum[64], s_sq[64];
  int m0 = blockIdx.x*32;
  int n0 = blockIdx.y*64;
  int tid  = threadIdx.x;
  int tcol = tid & 15, trow = tid >> 4;
  float acc[2][4] = {};
  constexpr int NCH = (K + 31) / 32;
  for (int ch = 0; ch < NCH; ch++){
    int kc0 = ch*32;
    {
      int rr = tid >> 3; int k4 = (tid & 7) << 2;
      int row = m0 + rr;
      int kg = kc0 + k4;
      float4 v = {0.f,0.f,0.f,0.f};
      if (row < nrows){
        if constexpr (CONCAT){
          if (kg < 256){
            v = *(const float4*)(A0 + (size_t)row*256 + kg);
            if constexpr (EMB){
              int c = gstart[row+1] - gstart[row];
              if (c > 0){
                float rinv = 1.0f / (float)c;
                float4 scv = *(const float4*)(esc + kg);
                float4 shv = *(const float4*)(esh + kg);
                v.x = fmaf(v.x*rinv, scv.x, shv.x);
                v.y = fmaf(v.y*rinv, scv.y, shv.y);
                v.z = fmaf(v.z*rinv, scv.z, shv.z);
                v.w = fmaf(v.w*rinv, scv.w, shv.w);
              } else { v.x=v.y=v.z=v.w=0.f; }
            }
          }
          else if (kg < 456) v = *(const float4*)(A1 + (size_t)row*200 + (kg-256));
        } else {
          v = *(const float4*)(A0 + (size_t)row*K + kg);
        }
      }
      if constexpr (AFFINE){
        float4 scv = *(const float4*)(scale + kg);
        float4 shv = *(const float4*)(shift + kg);
        v.x = fmaf(v.x, scv.x, shv.x);
        v.y = fmaf(v.y, scv.y, shv.y);
        v.z = fmaf(v.z, scv.z, shv.z);
        v.w = fmaf(v.w, scv.w, shv.w);
      }
      As[(k4+0)*69 + rr] = v.x;
      As[(k4+1)*69 + rr] = v.y;
      As[(k4+2)*69 + rr] = v.z;
      As[(k4+3)*69 + rr] = v.w;
    }
    #pragma unroll
    for (int j = 0; j < 2; j++){
      int fid = tid + j*256;
      int kk = fid >> 4; int c4 = (fid & 15) << 2;
      int kg = kc0 + kk;
      float4 v = {0.f,0.f,0.f,0.f};
      if (kg < K) v = *(const float4*)(W + (size_t)kg*NWTOT + n0 + c4);
      *(float4*)(Bs + kk*64 + c4) = v;
    }
    __syncthreads();
    #pragma unroll
    for (int kk = 0; kk < 32; kk++){
      float4 b = *(const float4*)(Bs + kk*64 + tcol*4);
      float a0 = As[kk*69 + trow*2];
      float a1 = As[kk*69 + trow*2 + 1];
      acc[0][0] = fmaf(a0, b.x, acc[0][0]);
      acc[0][1] = fmaf(a0, b.y, acc[0][1]);
      acc[0][2] = fmaf(a0, b.z, acc[0][2]);
      acc[0][3] = fmaf(a0, b.w, acc[0][3]);
      acc[1][0] = fmaf(a1, b.x, acc[1][0]);
      acc[1][1] = fmaf(a1, b.y, acc[1][1]);
      acc[1][2] = fmaf(a1, b.z, acc[1][2]);
      acc[1][3] = fmaf(a1, b.w, acc[1][3]);
    }
    __syncthreads();
  }
  if (tid < 64){ s_sum[tid] = 0.f; s_sq[tid] = 0.f; }
  __syncthreads();
  float4 bv = *(const float4*)(bias + n0 + tcol*4);
  float psum[4] = {0,0,0,0}, psq[4] = {0,0,0,0};
  #pragma unroll
  for (int r = 0; r < 2; r++){
    int row = m0 + trow*2 + r;
    if (row < nrows){
      float4 o;
      o.x = fmaxf(acc[r][0] + bv.x, 0.f);
      o.y = fmaxf(acc[r][1] + bv.y, 0.f);
      o.z = fmaxf(acc[r][2] + bv.z, 0.f);
      o.w = fmaxf(acc[r][3] + bv.w, 0.f);
      *(float4*)(out + (size_t)row*NWTOT + n0 + tcol*4) = o;
      psum[0] += o.x; psq[0] += o.x*o.x;
      psum[1] += o.y; psq[1] += o.y*o.y;
      psum[2] += o.z; psq[2] += o.z*o.z;
      psum[3] += o.w; psq[3] += o.w*o.w;
    }
  }
  #pragma unroll
  for (int c = 0; c < 4; c++){
    psum[c] += __shfl_xor(psum[c], 16); psum[c] += __shfl_xor(psum[c], 32);
    psq[c]  += __shfl_xor(psq[c], 16);  psq[c]  += __shfl_xor(psq[c], 32);
  }
  if ((tid & 48) == 0){
    int f0 = tcol*4;
    atomicAdd(&s_sum[f0+0], psum[0]); atomicAdd(&s_sq[f0+0], psq[0]);
    atomicAdd(&s_sum[f0+1], psum[1]); atomicAdd(&s_sq[f0+1], psq[1]);
    atomicAdd(&s_sum[f0+2], psum[2]); atomicAdd(&s_sq[f0+2], psq[2]);
    atomicAdd(&s_sum[f0+3], psum[3]); atomicAdd(&s_sq[f0+3], psq[3]);
  }
  __syncthreads();
  float* gs = gstats + (size_t)(blockIdx.x & (NSLICE-1))*(2*NWTOT);
  if (tid < 64){
    atomicAdd(&gs[n0 + tid], s_sum[tid]);
    atomicAdd(&gs[NWTOT + n0 + tid], s_sq[tid]);
  }
}

// ---------------- final ----------------
__global__ __launch_bounds__(256) void k_final(
    const float* __restrict__ a2, const float* __restrict__ sc, const float* __restrict__ sh,
    const float* __restrict__ w, const float* __restrict__ b, float* __restrict__ out, int G)
{
  int gid  = blockIdx.x*blockDim.x + threadIdx.x;
  int wid  = gid >> 6;
  int lane = gid & 63;
  if (wid >= G) return;
  float2 v = ((const float2*)(a2 + (size_t)wid*128))[lane];
  int k = lane*2;
  float s = fmaf(v.x, sc[k], sh[k]) * w[k] + fmaf(v.y, sc[k+1], sh[k+1]) * w[k+1];
  #pragma unroll
  for (int o = 32; o > 0; o >>= 1) s += __shfl_down(s, o, 64);
  if (lane == 0) out[wid] = s + b[0];
}

// ---------------- launcher ----------------
extern "C" void kernel_launch(void* const* d_in, const int* in_sizes, int n_in,
                              void* d_out, int out_size, void* d_ws, size_t ws_size,
                              hipStream_t stream)
{
  (void)n_in; (void)out_size; (void)ws_size;
  const float* x    = (const float*)d_in[0];
  const int*   ei   = (const int*)d_in[1];
  const int*   batch= (const int*)d_in[2];
  const float* rdk  = (const float*)d_in[3];
  const float* W1   = (const float*)d_in[4];
  const float* b1   = (const float*)d_in[5];
  const float* g1   = (const float*)d_in[6];
  const float* be1  = (const float*)d_in[7];
  const float* W2   = (const float*)d_in[8];
  const float* b2   = (const float*)d_in[9];
  const float* g2   = (const float*)d_in[10];
  const float* be2  = (const float*)d_in[11];
  const float* mW1  = (const float*)d_in[12];
  const float* mb1  = (const float*)d_in[13];
  const float* mg1  = (const float*)d_in[14];
  const float* mbe1 = (const float*)d_in[15];
  const float* mW2  = (const float*)d_in[16];
  const float* mb2  = (const float*)d_in[17];
  const float* mg2  = (const float*)d_in[18];
  const float* mbe2 = (const float*)d_in[19];
  const float* mW3  = (const float*)d_in[20];
  const float* mb3  = (const float*)d_in[21];

  const int N = in_sizes[0] / 64;
  const int E = in_sizes[1] / 2;
  const int G = in_sizes[3] / 200;
  const int* erow = ei;
  const int* ecol = ei + E;
  const int nb = (N + BK_SIZE - 1) >> BK_BITS;

  size_t off = 0;
  auto alloc = [&](size_t bytes)->char*{
    char* p = (char*)d_ws + off;
    off += (bytes + 255) & ~(size_t)255;
    return p;
  };
  int*   offs   = (int*)  alloc(((size_t)N+1)*4);
  int*   csr    = (int*)  alloc((size_t)E*4);
  uint32_t* ebuf= (uint32_t*)alloc((size_t)NBK_MAX*EB_CAP*4);
  int*   bbase  = (int*)  alloc(1025*4);
  int*   bcur   = (int*)  alloc(NBK_MAX*4);
  float* dinv   = (float*)alloc((size_t)N*4);
  float* dsum   = (float*)alloc((size_t)N*4);
  uint16_t* xs  = (uint16_t*)alloc((size_t)N*64*2);
  uint16_t* z1  = (uint16_t*)alloc(((size_t)N+16)*64*2);
  uint8_t*  u   = (uint8_t*)alloc((size_t)N*128);
  uint16_t* z2  = (uint16_t*)alloc(((size_t)N+16)*128*2);
  uint16_t* WT1 = (uint16_t*)alloc((size_t)128*64*2);
  uint16_t* WT2 = (uint16_t*)alloc((size_t)256*128*2);
  float* embsum = (float*)alloc((size_t)G*256*4);
  int*   gstart = (int*)  alloc(((size_t)G+1)*4);
  float* a1     = (float*)alloc((size_t)G*256*4);
  float* a2     = (float*)alloc((size_t)G*128*4);
  float* gstats = (float*)alloc((size_t)4*NSLICE*2*256*4);
  float* scsh   = (float*)alloc((size_t)4*2*256*4);

  float* gs0 = gstats;
  float* gs1 = gstats + NSLICE*2*256;
  float* gs2 = gstats + 2*NSLICE*2*256;
  float* gs3 = gstats + 3*NSLICE*2*256;
  float* sc1 = scsh;        float* sh1 = scsh + 256;
  float* sc2 = scsh + 512;  float* sh2 = scsh + 768;
  float* sc3 = scsh + 1024; float* sh3 = scsh + 1280;
  float* sc4 = scsh + 1536; float* sh4 = scsh + 1792;

  int cbN   = (N + 255) / 256;
  int mblk  = (N + 63) / 64;
  int gblk32= (G + 31) / 32;
  int ablk  = (E + PA_TILE - 1) / PA_TILE;

  k_misc<<<1280 + cbN + 1 + 32 + 128, 256, 0, stream>>>(
      batch, gstart, N, G, cbN, W1, WT1, W2, WT2, bcur,
      (float4*)gstats, (float4*)embsum);

  k_passA<<<ablk,256,0,stream>>>(erow, ecol, bcur, ebuf, E);
  k_bscan<<<1,256,0,stream>>>(bcur, bbase, E, nb);
  k_passB2<<<nb,256,0,stream>>>(ebuf, bbase, offs, dinv, csr, (const float4*)x, (ushort4*)xs, N, E, nb);

  k_agg1<<<(N+31)/32,256,0,stream>>>((const uint4*)xs, offs, csr, dinv, (uint4*)z1, dsum, N);
  k_gemm_mfma<64,128,false><<<mblk,256,0,stream>>>(z1, WT1, b1, nullptr, dinv, u, nullptr, gs0, N);
  k_bnfin<<<128,128,0,stream>>>(gs0, 128, 1.0f/(float)N, g1, be1, sc1, sh1);

  k_agg2<<<(N+31)/32,256,0,stream>>>((const uint4*)u, offs, csr, dinv, dsum, sc1, sh1, (uint4*)z2, N);
  k_gemm_mfma<128,256,true><<<mblk,256,0,stream>>>(z2, WT2, b2, batch, nullptr, nullptr, embsum, gs1, N);
  k_bnfin<<<256,128,0,stream>>>(gs1, 256, 1.0f/(float)N, g2, be2, sc2, sh2);

  k_gemm_mlp<456,256,true,false,true><<<dim3(gblk32,4),256,0,stream>>>(embsum, rdk, mW1, nullptr, nullptr, gstart, sc2, sh2, mb1, a1, gs2, G);
  k_bnfin<<<256,128,0,stream>>>(gs2, 256, 1.0f/(float)G, mg1, mbe1, sc3, sh3);
  k_gemm_mlp<256,128,false,true,false><<<dim3(gblk32,2),256,0,stream>>>(a1, nullptr, mW2, sc3, sh3, nullptr, nullptr, nullptr, mb2, a2, gs3, G);
  k_bnfin<<<128,128,0,stream>>>(gs3, 128, 1.0f/(float)G, mg2, mbe2, sc4, sh4);
  k_final<<<(G+3)/4,256,0,stream>>>(a2, sc4, sh4, mW3, mb3, (float*)d_out, G);
}

// Round 19
// 448.764 us; speedup vs baseline: 1.0513x; 1.0513x over previous
//
#include <hip/hip_runtime.h>
#include <cstdint>
#include <cstddef>

#define BN_EPS 1e-5f
#define NSLICE 128
#define BK_BITS 7
#define BK_SIZE 128
#define NBK_MAX 1024
#define EB_CAP 5120

typedef __attribute__((ext_vector_type(8))) __bf16 bf16x8;
typedef __attribute__((ext_vector_type(4))) float f32x4;
typedef __attribute__((ext_vector_type(2))) float f32x2;

// ---------------- helpers ----------------

__device__ inline uint16_t f2bf(float f){
  union {float f; uint32_t u;} v; v.f = f;
  uint32_t u = v.u;
  return (uint16_t)((u + 0x7FFFu + ((u >> 16) & 1u)) >> 16);
}

__device__ inline uint32_t pack2bf(float a, float b){
  return (uint32_t)f2bf(a) | ((uint32_t)f2bf(b) << 16);
}

__device__ inline void bf2f2(uint32_t w, float& a, float& b){
  union {uint32_t u; float f;} ua, ub;
  ua.u = w << 16; ub.u = w & 0xFFFF0000u;
  a = ua.f; b = ub.f;
}

__device__ inline uint8_t f2fp8(float v){
  uint32_t t = (uint32_t)__builtin_amdgcn_cvt_pk_fp8_f32(v, v, 0, false);
  return (uint8_t)(t & 0xFF);
}

__device__ inline void prepW_body(const float* W, uint16_t* WTf, int K, int NOUT, int id){
  if (id >= K*NOUT) return;
  int j    = id & 7;
  int l    = (id >> 3) & 63;
  int l15  = l & 15, quad = l >> 4;
  int rest = id >> 9;
  int KS   = K >> 5;
  int ks   = rest % KS;
  int t    = rest / KS;
  int k = ks*32 + quad*8 + j;
  int n = t*16 + l15;
  WTf[id] = f2bf(W[(size_t)k*NOUT + n]);
}

// ---------------- fused init ----------------
__global__ __launch_bounds__(256) void k_misc(
    const int* __restrict__ batch, int* __restrict__ gstart, int N, int G, int cbN,
    const float* __restrict__ W1, uint16_t* __restrict__ WT1,
    const float* __restrict__ W2, uint16_t* __restrict__ WT2,
    int* __restrict__ bcur,
    float4* __restrict__ gstats4, float4* __restrict__ embsum4)
{
  int b = blockIdx.x;
  int t = threadIdx.x;
  float4 z4 = {0.f,0.f,0.f,0.f};
  if (b < 256){
    gstats4[b*256 + t] = z4;
  } else if (b < 1280){
    embsum4[(b-256)*256 + t] = z4;
  } else if (b < 1280 + cbN){
    int i = (b-1280)*256 + t;
    if (i < N){
      int bb = batch[i];
      int bp = (i > 0) ? batch[i-1] : -1;
      for (int g = bp+1; g <= bb; g++) gstart[g] = i;
      if (i == N-1){
        for (int g = bb+1; g <= G; g++) gstart[g] = N;
      }
    }
  } else if (b == 1280 + cbN){
    for (int i = t; i < NBK_MAX; i += 256) bcur[i] = i * EB_CAP;
  } else if (b < 1280 + cbN + 1 + 32){
    prepW_body(W1, WT1, 64, 128, (b - 1280 - cbN - 1)*256 + t);
  } else {
    prepW_body(W2, WT2, 128, 256, (b - 1280 - cbN - 33)*256 + t);
  }
}

// ---------------- graph preprocessing: 128-node buckets, single-phase passA ----------------
#define PA_TILE 4096

__global__ __launch_bounds__(256) void k_passA(
    const int* __restrict__ row, const int* __restrict__ col,
    int* __restrict__ bcur, uint32_t* __restrict__ ebuf, int E)
{
  __shared__ int hist[NBK_MAX];
  __shared__ int rbase[NBK_MAX];
  int t = threadIdx.x;
  int start = blockIdx.x * PA_TILE;
  for (int i = t; i < NBK_MAX; i += 256) hist[i] = 0;
  __syncthreads();
  uint32_t myv[16]; int myb[16];
  #pragma unroll
  for (int j = 0; j < 16; j++){
    int e = start + t + j*256;
    if (e < E){
      int r = row[e], c = col[e];
      myb[j] = c >> BK_BITS;
      myv[j] = ((uint32_t)r << BK_BITS) | (uint32_t)(c & (BK_SIZE-1));
      atomicAdd(&hist[myb[j]], 1);
    } else myb[j] = -1;
  }
  __syncthreads();
  for (int i = t; i < NBK_MAX; i += 256){
    int h = hist[i];
    rbase[i] = (h > 0) ? atomicAdd(&bcur[i], h) : 0;
  }
  __syncthreads();
  for (int i = t; i < NBK_MAX; i += 256) hist[i] = 0;
  __syncthreads();
  #pragma unroll
  for (int j = 0; j < 16; j++){
    if (myb[j] >= 0){
      int pos = rbase[myb[j]] + atomicAdd(&hist[myb[j]], 1);
      ebuf[pos] = myv[j];
    }
  }
}

__global__ __launch_bounds__(256) void k_bscan(const int* __restrict__ bcur,
                                               int* __restrict__ bbase, int E, int nb){
  __shared__ int s[256];
  int t = threadIdx.x;
  int base = t*4;
  int v0 = (base+0 < nb) ? (bcur[base+0] - (base+0)*EB_CAP) : 0;
  int v1 = (base+1 < nb) ? (bcur[base+1] - (base+1)*EB_CAP) : 0;
  int v2 = (base+2 < nb) ? (bcur[base+2] - (base+2)*EB_CAP) : 0;
  int v3 = (base+3 < nb) ? (bcur[base+3] - (base+3)*EB_CAP) : 0;
  int lsum = v0+v1+v2+v3;
  s[t] = lsum;
  __syncthreads();
  for (int off=1; off<256; off<<=1){
    int x = 0;
    if (t >= off) x = s[t-off];
    __syncthreads();
    if (t >= off) s[t] += x;
    __syncthreads();
  }
  int excl = s[t] - lsum;
  bbase[base+0] = excl;
  bbase[base+1] = excl + v0;
  bbase[base+2] = excl + v0 + v1;
  bbase[base+3] = excl + v0 + v1 + v2;
  if (t == 255) bbase[1024] = E;
}

// passB2 (128-node buckets) + fused x->xs conversion
__global__ __launch_bounds__(256) void k_passB2(
    const uint32_t* __restrict__ ebuf, const int* __restrict__ bbase,
    int* __restrict__ offs, float* __restrict__ dinv,
    int* __restrict__ csr,
    const float4* __restrict__ x, ushort4* __restrict__ xs,
    int N, int E, int nb)
{
  __shared__ int deg[BK_SIZE];
  __shared__ int cur[BK_SIZE];
  __shared__ int ps[BK_SIZE];
  int b = blockIdx.x;
  int base = b << BK_BITS;
  int t = threadIdx.x;
  int s = bbase[b], e = bbase[b+1];
  int ecnt = e - s;
  const uint32_t* eb = ebuf + (size_t)b*EB_CAP;
  if (t < BK_SIZE) deg[t] = 0;
  __syncthreads();
  for (int i = t; i < ecnt; i += 256)
    atomicAdd(&deg[eb[i] & (BK_SIZE-1u)], 1);
  __syncthreads();
  int d = (t < BK_SIZE) ? deg[t] : 0;
  if (t < BK_SIZE) ps[t] = d;
  __syncthreads();
  for (int off=1; off<BK_SIZE; off<<=1){
    int x_ = 0;
    if (t < BK_SIZE && t >= off) x_ = ps[t-off];
    __syncthreads();
    if (t < BK_SIZE && t >= off) ps[t] += x_;
    __syncthreads();
  }
  if (t < BK_SIZE){
    int o = s + ps[t] - d;
    cur[t] = o;
    int n0 = base + t;
    if (n0 < N){ offs[n0] = o; dinv[n0] = 1.0f / sqrtf((float)(d + 1)); }
  }
  if (b == nb-1 && t == 0) offs[N] = E;
  __syncthreads();
  for (int i = t; i < ecnt; i += 256){
    uint32_t v = eb[i];
    int local = v & (BK_SIZE-1u);
    int pos = atomicAdd(&cur[local], 1);
    csr[pos] = (int)(v >> BK_BITS);
  }
  for (int idx = t; idx < BK_SIZE*16; idx += 256){
    int local = idx >> 4;
    int node = base + local;
    if (node < N){
      float dd = 1.0f / sqrtf((float)(deg[local] + 1));
      int c16 = idx & 15;
      float4 v = x[(size_t)node*16 + c16];
      ushort4 o;
      o.x = f2bf(v.x*dd); o.y = f2bf(v.y*dd); o.z = f2bf(v.z*dd); o.w = f2bf(v.w*dd);
      xs[(size_t)node*16 + c16] = o;
    }
  }
}

// parallel bn finalize: one block per column, slice-parallel tree reduce
__global__ __launch_bounds__(128) void k_bnfin(const float* __restrict__ region, int F, float invCount,
                        const float* __restrict__ g, const float* __restrict__ be,
                        float* __restrict__ scale, float* __restrict__ shift){
  __shared__ float ss[128], sq[128];
  int i  = blockIdx.x;
  int sl = threadIdx.x;
  ss[sl] = region[sl*2*F + i];
  sq[sl] = region[sl*2*F + F + i];
  __syncthreads();
  for (int off = 64; off > 0; off >>= 1){
    if (sl < off){ ss[sl] += ss[sl+off]; sq[sl] += sq[sl+off]; }
    __syncthreads();
  }
  if (sl == 0){
    float mu  = ss[0] * invCount;
    float var = sq[0] * invCount - mu*mu;
    if (var < 0.f) var = 0.f;
    float rstd = 1.0f / sqrtf(var + BN_EPS);
    float sc = g[i] * rstd;
    scale[i] = sc;
    shift[i] = be[i] - mu * sc;
  }
}

// ---------------- aggregation kernels ----------------
__global__ __launch_bounds__(256) void k_agg1(
    const uint4* __restrict__ xs, const int* __restrict__ offs, const int* __restrict__ csr,
    const float* __restrict__ dinv, uint4* __restrict__ z, float* __restrict__ dsum, int N)
{
  int sub = threadIdx.x >> 3, lane = threadIdx.x & 7;
  int node = blockIdx.x*32 + sub;
  if (node >= N) return;
  int s = offs[node], e = offs[node+1];
  float acc[8] = {};
  float ds = 0.f;
  auto add8 = [&](uint4 v){
    float f0,f1,f2,f3,f4,f5,f6,f7;
    bf2f2(v.x, f0, f1); bf2f2(v.y, f2, f3);
    bf2f2(v.z, f4, f5); bf2f2(v.w, f6, f7);
    acc[0]+=f0; acc[1]+=f1; acc[2]+=f2; acc[3]+=f3;
    acc[4]+=f4; acc[5]+=f5; acc[6]+=f6; acc[7]+=f7;
  };
  int i = s;
  for (; i + 4 <= e; i += 4){
    int r0 = csr[i], r1 = csr[i+1], r2 = csr[i+2], r3 = csr[i+3];
    uint4 v0 = xs[r0*8 + lane];
    uint4 v1 = xs[r1*8 + lane];
    uint4 v2 = xs[r2*8 + lane];
    uint4 v3 = xs[r3*8 + lane];
    add8(v0); add8(v1); add8(v2); add8(v3);
    if (lane == 0) ds += dinv[r0] + dinv[r1] + dinv[r2] + dinv[r3];
  }
  for (; i < e; i++){
    int r0 = csr[i];
    add8(xs[r0*8 + lane]);
    if (lane == 0) ds += dinv[r0];
  }
  add8(xs[node*8 + lane]);
  float d = dinv[node];
  if (lane == 0) dsum[node] = ds + d;
  uint4 o;
  o.x = pack2bf(acc[0]*d, acc[1]*d);
  o.y = pack2bf(acc[2]*d, acc[3]*d);
  o.z = pack2bf(acc[4]*d, acc[5]*d);
  o.w = pack2bf(acc[6]*d, acc[7]*d);
  z[(node>>4)*128 + lane*16 + (node&15)] = o;
}

// agg2: gather u (fp8, 16B/lane, 8 lanes/node) -> algebraic bn1 affine -> z2
__global__ __launch_bounds__(256) void k_agg2(
    const uint4* __restrict__ u, const int* __restrict__ offs, const int* __restrict__ csr,
    const float* __restrict__ dinv, const float* __restrict__ dsum,
    const float* __restrict__ sc1, const float* __restrict__ sh1,
    uint4* __restrict__ z, int N)
{
  int sub = threadIdx.x >> 3, lane = threadIdx.x & 7;
  int node = blockIdx.x*32 + sub;
  if (node >= N) return;
  int s = offs[node], e = offs[node+1];
  float acc[16] = {};
  auto add16 = [&](uint4 v){
    f32x2 p;
    p = __builtin_amdgcn_cvt_pk_f32_fp8((int)v.x, false); acc[0]+=p.x;  acc[1]+=p.y;
    p = __builtin_amdgcn_cvt_pk_f32_fp8((int)v.x, true ); acc[2]+=p.x;  acc[3]+=p.y;
    p = __builtin_amdgcn_cvt_pk_f32_fp8((int)v.y, false); acc[4]+=p.x;  acc[5]+=p.y;
    p = __builtin_amdgcn_cvt_pk_f32_fp8((int)v.y, true ); acc[6]+=p.x;  acc[7]+=p.y;
    p = __builtin_amdgcn_cvt_pk_f32_fp8((int)v.z, false); acc[8]+=p.x;  acc[9]+=p.y;
    p = __builtin_amdgcn_cvt_pk_f32_fp8((int)v.z, true ); acc[10]+=p.x; acc[11]+=p.y;
    p = __builtin_amdgcn_cvt_pk_f32_fp8((int)v.w, false); acc[12]+=p.x; acc[13]+=p.y;
    p = __builtin_amdgcn_cvt_pk_f32_fp8((int)v.w, true ); acc[14]+=p.x; acc[15]+=p.y;
  };
  int i = s;
  for (; i + 4 <= e; i += 4){
    int r0 = csr[i], r1 = csr[i+1], r2 = csr[i+2], r3 = csr[i+3];
    uint4 v0 = u[r0*8 + lane];
    uint4 v1 = u[r1*8 + lane];
    uint4 v2 = u[r2*8 + lane];
    uint4 v3 = u[r3*8 + lane];
    add16(v0); add16(v1); add16(v2); add16(v3);
  }
  for (; i < e; i++) add16(u[csr[i]*8 + lane]);
  add16(u[node*8 + lane]);
  float d  = dinv[node];
  float ds = dsum[node];
  int f0 = lane*16;
  uint4 o0, o1;
  {
    float4 sa = *(const float4*)(sc1 + f0);
    float4 sb = *(const float4*)(sc1 + f0 + 4);
    float4 ha = *(const float4*)(sh1 + f0);
    float4 hb = *(const float4*)(sh1 + f0 + 4);
    o0.x = pack2bf(d*fmaf(sa.x, acc[0], ha.x*ds), d*fmaf(sa.y, acc[1], ha.y*ds));
    o0.y = pack2bf(d*fmaf(sa.z, acc[2], ha.z*ds), d*fmaf(sa.w, acc[3], ha.w*ds));
    o0.z = pack2bf(d*fmaf(sb.x, acc[4], hb.x*ds), d*fmaf(sb.y, acc[5], hb.y*ds));
    o0.w = pack2bf(d*fmaf(sb.z, acc[6], hb.z*ds), d*fmaf(sb.w, acc[7], hb.w*ds));
  }
  {
    float4 sa = *(const float4*)(sc1 + f0 + 8);
    float4 sb = *(const float4*)(sc1 + f0 + 12);
    float4 ha = *(const float4*)(sh1 + f0 + 8);
    float4 hb = *(const float4*)(sh1 + f0 + 12);
    o1.x = pack2bf(d*fmaf(sa.x, acc[8],  ha.x*ds), d*fmaf(sa.y, acc[9],  ha.y*ds));
    o1.y = pack2bf(d*fmaf(sa.z, acc[10], ha.z*ds), d*fmaf(sa.w, acc[11], ha.w*ds));
    o1.z = pack2bf(d*fmaf(sb.x, acc[12], hb.x*ds), d*fmaf(sb.y, acc[13], hb.y*ds));
    o1.w = pack2bf(d*fmaf(sb.z, acc[14], hb.z*ds), d*fmaf(sb.w, acc[15], hb.w*ds));
  }
  size_t zb = (size_t)(node>>4)*256 + (node&15);
  z[zb + (2*lane)*16]   = o0;
  z[zb + (2*lane+1)*16] = o1;
}

// ---------------- MFMA node GEMM ----------------
template<int K, int NOUT, bool POOL>
__global__ __launch_bounds__(256) void k_gemm_mfma(
    const uint16_t* __restrict__ A, const uint16_t* __restrict__ WTf,
    const float* __restrict__ bias, const int* __restrict__ batch,
    const float* __restrict__ dinv,
    uint8_t* __restrict__ u_out, float* __restrict__ embsum,
    float* __restrict__ gstats, int N)
{
  constexpr int NT = NOUT/16;
  constexpr int KS = K/32;
  constexpr int TRS8 = NOUT + 16;
  constexpr int TRSF = NOUT + 8;
  __shared__ float s_bias[NOUT];
  __shared__ int s_batch[64];
  __shared__ float s_dinv[POOL ? 1 : 64];
  __shared__ float s_sum[POOL ? 1 : NOUT];
  __shared__ float s_sq[POOL ? 1 : NOUT];
  __shared__ float s_trf[POOL ? 64*TRSF : 1];
  __shared__ uint8_t s_tr8[POOL ? 16 : 64*TRS8];
  int tid = threadIdx.x;
  int w = tid >> 6;
  int lane = tid & 63;
  int l15 = lane & 15, quad = lane >> 4;
  int m0 = blockIdx.x * 64;
  for (int i = tid; i < NOUT; i += 256) s_bias[i] = bias[i];
  if constexpr (!POOL){
    for (int i = tid; i < NOUT; i += 256){ s_sum[i]=0.f; s_sq[i]=0.f; }
    if (tid < 64) s_dinv[tid] = (m0+tid < N) ? dinv[m0+tid] : 0.f;
  }
  if (POOL && tid < 64) s_batch[tid] = (m0+tid < N) ? batch[m0+tid] : -1;
  __syncthreads();

  const uint16_t* Ag = A + (size_t)(m0/16 + w)*(16*K);

  f32x4 acc[NT];
  #pragma unroll
  for (int t=0;t<NT;t++) acc[t] = (f32x4){0.f,0.f,0.f,0.f};

  #pragma unroll
  for (int ks=0; ks<KS; ks++){
    bf16x8 af = *(const bf16x8*)(Ag + (ks*4 + quad)*128 + l15*8);
    #pragma unroll
    for (int t=0;t<NT;t++){
      bf16x8 bw = *(const bf16x8*)(WTf + (((size_t)(t*KS + ks)*64 + lane) << 3));
      acc[t] = __builtin_amdgcn_mfma_f32_16x16x32_bf16(af, bw, acc[t], 0, 0, 0);
    }
  }

  int rloc = w*16 + quad*4;
  if constexpr (POOL){
    #pragma unroll
    for (int t=0;t<NT;t++){
      int n = t*16 + l15;
      float bv = s_bias[n];
      #pragma unroll
      for (int r=0;r<4;r++){
        bool valid = (m0 + rloc + r) < N;
        float val = fmaxf(acc[t][r] + bv, 0.f);
        s_trf[(rloc + r)*TRSF + n] = valid ? val : 0.f;
      }
    }
    __syncthreads();
    {
      int n = tid;
      float vs = 0.f, vq = 0.f;
      int cur = -1; float run = 0.f;
      #pragma unroll 8
      for (int row = 0; row < 64; row++){
        float v = s_trf[row*TRSF + n];
        vs += v; vq += v*v;
        int b = s_batch[row];
        if (b != cur){
          if (cur >= 0 && run != 0.f) atomicAdd(&embsum[(size_t)cur*NOUT + n], run);
          cur = b; run = v;
        } else run += v;
      }
      if (cur >= 0 && run != 0.f) atomicAdd(&embsum[(size_t)cur*NOUT + n], run);
      float* gs = gstats + (size_t)(blockIdx.x & (NSLICE-1))*(2*NOUT);
      atomicAdd(&gs[n], vs);
      atomicAdd(&gs[NOUT + n], vq);
    }
  } else {
    #pragma unroll
    for (int t=0;t<NT;t++){
      int n = t*16 + l15;
      float bv = s_bias[n];
      float vs = 0.f, vq = 0.f;
      #pragma unroll
      for (int r=0;r<4;r++){
        bool valid = (m0 + rloc + r) < N;
        float val = fmaxf(acc[t][r] + bv, 0.f);
        float o = valid ? val : 0.f;
        vs += o; vq += o*o;
        s_tr8[(rloc + r)*TRS8 + n] = f2fp8(o * s_dinv[rloc + r]);
      }
      vs += __shfl_xor(vs, 16); vs += __shfl_xor(vs, 32);
      vq += __shfl_xor(vq, 16); vq += __shfl_xor(vq, 32);
      if (quad == 0){
        atomicAdd(&s_sum[n], vs);
        atomicAdd(&s_sq[n], vq);
      }
    }
    __syncthreads();
    constexpr int CPR = NOUT/16;
    for (int i = tid; i < 64*CPR; i += 256){
      int row = i / CPR, c = i - row*CPR;
      int grow = m0 + row;
      if (grow < N)
        *(uint4*)(u_out + (size_t)grow*NOUT + c*16) = *(const uint4*)(s_tr8 + row*TRS8 + c*16);
    }
    float* gs = gstats + (size_t)(blockIdx.x & (NSLICE-1))*(2*NOUT);
    for (int i = tid; i < NOUT; i += 256){
      atomicAdd(&gs[i], s_sum[i]);
      atomicAdd(&gs[NOUT + i], s_sq[i]);
    }
  }
}

// ---------------- GEMM (head MLP, fp32), 32-row x 64-col tiles ----------------
template<int K, int NWTOT, bool CONCAT, bool AFFINE, bool EMB>
__global__ __launch_bounds__(256) void k_gemm_mlp(
    const float* __restrict__ A0, const float* __restrict__ A1,
    const float* __restrict__ W,
    const float* __restrict__ scale, const float* __restrict__ shift,
    const int* __restrict__ gstart, const float* __restrict__ esc, const float* __restrict__ esh,
    const float* __restrict__ bias,
    float* __restrict__ out, float* __restrict__ gstats, int nrows)
{
  __shared__ float As[32*69];
  __shared__ float Bs[32*64];
  __shared__ float s_sum[64], s_sq[64];
  int m0 = blockIdx.x*32;
  int n0 = blockIdx.y*64;
  int tid  = threadIdx.x;
  int tcol = tid & 15, trow = tid >> 4;
  float acc[2][4] = {};
  constexpr int NCH = (K + 31) / 32;
  for (int ch = 0; ch < NCH; ch++){
    int kc0 = ch*32;
    {
      int rr = tid >> 3; int k4 = (tid & 7) << 2;
      int row = m0 + rr;
      int kg = kc0 + k4;
      float4 v = {0.f,0.f,0.f,0.f};
      if (row < nrows){
        if constexpr (CONCAT){
          if (kg < 256){
            v = *(const float4*)(A0 + (size_t)row*256 + kg);
            if constexpr (EMB){
              int c = gstart[row+1] - gstart[row];
              if (c > 0){
                float rinv = 1.0f / (float)c;
                float4 scv = *(const float4*)(esc + kg);
                float4 shv = *(const float4*)(esh + kg);
                v.x = fmaf(v.x*rinv, scv.x, shv.x);
                v.y = fmaf(v.y*rinv, scv.y, shv.y);
                v.z = fmaf(v.z*rinv, scv.z, shv.z);
                v.w = fmaf(v.w*rinv, scv.w, shv.w);
              } else { v.x=v.y=v.z=v.w=0.f; }
            }
          }
          else if (kg < 456) v = *(const float4*)(A1 + (size_t)row*200 + (kg-256));
        } else {
          v = *(const float4*)(A0 + (size_t)row*K + kg);
        }
      }
      if constexpr (AFFINE){
        float4 scv = *(const float4*)(scale + kg);
        float4 shv = *(const float4*)(shift + kg);
        v.x = fmaf(v.x, scv.x, shv.x);
        v.y = fmaf(v.y, scv.y, shv.y);
        v.z = fmaf(v.z, scv.z, shv.z);
        v.w = fmaf(v.w, scv.w, shv.w);
      }
      As[(k4+0)*69 + rr] = v.x;
      As[(k4+1)*69 + rr] = v.y;
      As[(k4+2)*69 + rr] = v.z;
      As[(k4+3)*69 + rr] = v.w;
    }
    #pragma unroll
    for (int j = 0; j < 2; j++){
      int fid = tid + j*256;
      int kk = fid >> 4; int c4 = (fid & 15) << 2;
      int kg = kc0 + kk;
      float4 v = {0.f,0.f,0.f,0.f};
      if (kg < K) v = *(const float4*)(W + (size_t)kg*NWTOT + n0 + c4);
      *(float4*)(Bs + kk*64 + c4) = v;
    }
    __syncthreads();
    #pragma unroll
    for (int kk = 0; kk < 32; kk++){
      float4 b = *(const float4*)(Bs + kk*64 + tcol*4);
      float a0 = As[kk*69 + trow*2];
      float a1 = As[kk*69 + trow*2 + 1];
      acc[0][0] = fmaf(a0, b.x, acc[0][0]);
      acc[0][1] = fmaf(a0, b.y, acc[0][1]);
      acc[0][2] = fmaf(a0, b.z, acc[0][2]);
      acc[0][3] = fmaf(a0, b.w, acc[0][3]);
      acc[1][0] = fmaf(a1, b.x, acc[1][0]);
      acc[1][1] = fmaf(a1, b.y, acc[1][1]);
      acc[1][2] = fmaf(a1, b.z, acc[1][2]);
      acc[1][3] = fmaf(a1, b.w, acc[1][3]);
    }
    __syncthreads();
  }
  if (tid < 64){ s_sum[tid] = 0.f; s_sq[tid] = 0.f; }
  __syncthreads();
  float4 bv = *(const float4*)(bias + n0 + tcol*4);
  float psum[4] = {0,0,0,0}, psq[4] = {0,0,0,0};
  #pragma unroll
  for (int r = 0; r < 2; r++){
    int row = m0 + trow*2 + r;
    if (row < nrows){
      float4 o;
      o.x = fmaxf(acc[r][0] + bv.x, 0.f);
      o.y = fmaxf(acc[r][1] + bv.y, 0.f);
      o.z = fmaxf(acc[r][2] + bv.z, 0.f);
      o.w = fmaxf(acc[r][3] + bv.w, 0.f);
      *(float4*)(out + (size_t)row*NWTOT + n0 + tcol*4) = o;
      psum[0] += o.x; psq[0] += o.x*o.x;
      psum[1] += o.y; psq[1] += o.y*o.y;
      psum[2] += o.z; psq[2] += o.z*o.z;
      psum[3] += o.w; psq[3] += o.w*o.w;
    }
  }
  #pragma unroll
  for (int c = 0; c < 4; c++){
    psum[c] += __shfl_xor(psum[c], 16); psum[c] += __shfl_xor(psum[c], 32);
    psq[c]  += __shfl_xor(psq[c], 16);  psq[c]  += __shfl_xor(psq[c], 32);
  }
  if ((tid & 48) == 0){
    int f0 = tcol*4;
    atomicAdd(&s_sum[f0+0], psum[0]); atomicAdd(&s_sq[f0+0], psq[0]);
    atomicAdd(&s_sum[f0+1], psum[1]); atomicAdd(&s_sq[f0+1], psq[1]);
    atomicAdd(&s_sum[f0+2], psum[2]); atomicAdd(&s_sq[f0+2], psq[2]);
    atomicAdd(&s_sum[f0+3], psum[3]); atomicAdd(&s_sq[f0+3], psq[3]);
  }
  __syncthreads();
  float* gs = gstats + (size_t)(blockIdx.x & (NSLICE-1))*(2*NWTOT);
  if (tid < 64){
    atomicAdd(&gs[n0 + tid], s_sum[tid]);
    atomicAdd(&gs[NWTOT + n0 + tid], s_sq[tid]);
  }
}

// ---------------- final ----------------
__global__ __launch_bounds__(256) void k_final(
    const float* __restrict__ a2, const float* __restrict__ sc, const float* __restrict__ sh,
    const float* __restrict__ w, const float* __restrict__ b, float* __restrict__ out, int G)
{
  int gid  = blockIdx.x*blockDim.x + threadIdx.x;
  int wid  = gid >> 6;
  int lane = gid & 63;
  if (wid >= G) return;
  float2 v = ((const float2*)(a2 + (size_t)wid*128))[lane];
  int k = lane*2;
  float s = fmaf(v.x, sc[k], sh[k]) * w[k] + fmaf(v.y, sc[k+1], sh[k+1]) * w[k+1];
  #pragma unroll
  for (int o = 32; o > 0; o >>= 1) s += __shfl_down(s, o, 64);
  if (lane == 0) out[wid] = s + b[0];
}

// ---------------- launcher ----------------
extern "C" void kernel_launch(void* const* d_in, const int* in_sizes, int n_in,
                              void* d_out, int out_size, void* d_ws, size_t ws_size,
                              hipStream_t stream)
{
  (void)n_in; (void)out_size; (void)ws_size;
  const float* x    = (const float*)d_in[0];
  const int*   ei   = (const int*)d_in[1];
  const int*   batch= (const int*)d_in[2];
  const float* rdk  = (const float*)d_in[3];
  const float* W1   = (const float*)d_in[4];
  const float* b1   = (const float*)d_in[5];
  const float* g1   = (const float*)d_in[6];
  const float* be1  = (const float*)d_in[7];
  const float* W2   = (const float*)d_in[8];
  const float* b2   = (const float*)d_in[9];
  const float* g2   = (const float*)d_in[10];
  const float* be2  = (const float*)d_in[11];
  const float* mW1  = (const float*)d_in[12];
  const float* mb1  = (const float*)d_in[13];
  const float* mg1  = (const float*)d_in[14];
  const float* mbe1 = (const float*)d_in[15];
  const float* mW2  = (const float*)d_in[16];
  const float* mb2  = (const float*)d_in[17];
  const float* mg2  = (const float*)d_in[18];
  const float* mbe2 = (const float*)d_in[19];
  const float* mW3  = (const float*)d_in[20];
  const float* mb3  = (const float*)d_in[21];

  const int N = in_sizes[0] / 64;
  const int E = in_sizes[1] / 2;
  const int G = in_sizes[3] / 200;
  const int* erow = ei;
  const int* ecol = ei + E;
  const int nb = (N + BK_SIZE - 1) >> BK_BITS;

  size_t off = 0;
  auto alloc = [&](size_t bytes)->char*{
    char* p = (char*)d_ws + off;
    off += (bytes + 255) & ~(size_t)255;
    return p;
  };
  int*   offs   = (int*)  alloc(((size_t)N+1)*4);
  int*   csr    = (int*)  alloc((size_t)E*4);
  uint32_t* ebuf= (uint32_t*)alloc((size_t)NBK_MAX*EB_CAP*4);
  int*   bbase  = (int*)  alloc(1025*4);
  int*   bcur   = (int*)  alloc(NBK_MAX*4);
  float* dinv   = (float*)alloc((size_t)N*4);
  float* dsum   = (float*)alloc((size_t)N*4);
  uint16_t* xs  = (uint16_t*)alloc((size_t)N*64*2);
  uint16_t* z1  = (uint16_t*)alloc(((size_t)N+16)*64*2);
  uint8_t*  u   = (uint8_t*)alloc((size_t)N*128);
  uint16_t* z2  = (uint16_t*)alloc(((size_t)N+16)*128*2);
  uint16_t* WT1 = (uint16_t*)alloc((size_t)128*64*2);
  uint16_t* WT2 = (uint16_t*)alloc((size_t)256*128*2);
  float* embsum = (float*)alloc((size_t)G*256*4);
  int*   gstart = (int*)  alloc(((size_t)G+1)*4);
  float* a1     = (float*)alloc((size_t)G*256*4);
  float* a2     = (float*)alloc((size_t)G*128*4);
  float* gstats = (float*)alloc((size_t)4*NSLICE*2*256*4);
  float* scsh   = (float*)alloc((size_t)4*2*256*4);

  float* gs0 = gstats;
  float* gs1 = gstats + NSLICE*2*256;
  float* gs2 = gstats + 2*NSLICE*2*256;
  float* gs3 = gstats + 3*NSLICE*2*256;
  float* sc1 = scsh;        float* sh1 = scsh + 256;
  float* sc2 = scsh + 512;  float* sh2 = scsh + 768;
  float* sc3 = scsh + 1024; float* sh3 = scsh + 1280;
  float* sc4 = scsh + 1536; float* sh4 = scsh + 1792;

  int cbN   = (N + 255) / 256;
  int mblk  = (N + 63) / 64;
  int gblk32= (G + 31) / 32;
  int ablk  = (E + PA_TILE - 1) / PA_TILE;

  k_misc<<<1280 + cbN + 1 + 32 + 128, 256, 0, stream>>>(
      batch, gstart, N, G, cbN, W1, WT1, W2, WT2, bcur,
      (float4*)gstats, (float4*)embsum);

  k_passA<<<ablk,256,0,stream>>>(erow, ecol, bcur, ebuf, E);
  k_bscan<<<1,256,0,stream>>>(bcur, bbase, E, nb);
  k_passB2<<<nb,256,0,stream>>>(ebuf, bbase, offs, dinv, csr, (const float4*)x, (ushort4*)xs, N, E, nb);

  k_agg1<<<(N+31)/32,256,0,stream>>>((const uint4*)xs, offs, csr, dinv, (uint4*)z1, dsum, N);
  k_gemm_mfma<64,128,false><<<mblk,256,0,stream>>>(z1, WT1, b1, nullptr, dinv, u, nullptr, gs0, N);
  k_bnfin<<<128,128,0,stream>>>(gs0, 128, 1.0f/(float)N, g1, be1, sc1, sh1);

  k_agg2<<<(N+31)/32,256,0,stream>>>((const uint4*)u, offs, csr, dinv, dsum, sc1, sh1, (uint4*)z2, N);
  k_gemm_mfma<128,256,true><<<mblk,256,0,stream>>>(z2, WT2, b2, batch, nullptr, nullptr, embsum, gs1, N);
  k_bnfin<<<256,128,0,stream>>>(gs1, 256, 1.0f/(float)N, g2, be2, sc2, sh2);

  k_gemm_mlp<456,256,true,false,true><<<dim3(gblk32,4),256,0,stream>>>(embsum, rdk, mW1, nullptr, nullptr, gstart, sc2, sh2, mb1, a1, gs2, G);
  k_bnfin<<<256,128,0,stream>>>(gs2, 256, 1.0f/(float)G, mg1, mbe1, sc3, sh3);
  k_gemm_mlp<256,128,false,true,false><<<dim3(gblk32,2),256,0,stream>>>(a1, nullptr, mW2, sc3, sh3, nullptr, nullptr, nullptr, mb2, a2, gs3, G);
  k_bnfin<<<128,128,0,stream>>>(gs3, 128, 1.0f/(float)G, mg2, mbe2, sc4, sh4);
  k_final<<<(G+3)/4,256,0,stream>>>(a2, sc4, sh4, mW3, mb3, (float*)d_out, G);
}

// Round 20
// 438.672 us; speedup vs baseline: 1.0755x; 1.0230x over previous
//
#include <hip/hip_runtime.h>
#include <cstdint>
#include <cstddef>

#define BN_EPS 1e-5f
#define NSLICE 128
#define BK_BITS 7
#define BK_SIZE 128
#define NBK_MAX 1024
#define EB_CAP 5120

typedef __attribute__((ext_vector_type(8))) __bf16 bf16x8;
typedef __attribute__((ext_vector_type(4))) float f32x4;
typedef __attribute__((ext_vector_type(2))) float f32x2;

// ---------------- helpers ----------------

__device__ inline uint16_t f2bf(float f){
  union {float f; uint32_t u;} v; v.f = f;
  uint32_t u = v.u;
  return (uint16_t)((u + 0x7FFFu + ((u >> 16) & 1u)) >> 16);
}

__device__ inline uint32_t pack2bf(float a, float b){
  return (uint32_t)f2bf(a) | ((uint32_t)f2bf(b) << 16);
}

__device__ inline void bf2f2(uint32_t w, float& a, float& b){
  union {uint32_t u; float f;} ua, ub;
  ua.u = w << 16; ub.u = w & 0xFFFF0000u;
  a = ua.f; b = ub.f;
}

__device__ inline uint8_t f2fp8(float v){
  uint32_t t = (uint32_t)__builtin_amdgcn_cvt_pk_fp8_f32(v, v, 0, false);
  return (uint8_t)(t & 0xFF);
}

__device__ inline void prepW_body(const float* W, uint16_t* WTf, int K, int NOUT, int id){
  if (id >= K*NOUT) return;
  int j    = id & 7;
  int l    = (id >> 3) & 63;
  int l15  = l & 15, quad = l >> 4;
  int rest = id >> 9;
  int KS   = K >> 5;
  int ks   = rest % KS;
  int t    = rest / KS;
  int k = ks*32 + quad*8 + j;
  int n = t*16 + l15;
  WTf[id] = f2bf(W[(size_t)k*NOUT + n]);
}

// ---------------- fused init ----------------
__global__ __launch_bounds__(256) void k_misc(
    const int* __restrict__ batch, int* __restrict__ gstart, int N, int G, int cbN,
    const float* __restrict__ W1, uint16_t* __restrict__ WT1,
    const float* __restrict__ W2, uint16_t* __restrict__ WT2,
    int* __restrict__ bcur,
    float4* __restrict__ gstats4, float4* __restrict__ embsum4)
{
  int b = blockIdx.x;
  int t = threadIdx.x;
  float4 z4 = {0.f,0.f,0.f,0.f};
  if (b < 256){
    gstats4[b*256 + t] = z4;
  } else if (b < 1280){
    embsum4[(b-256)*256 + t] = z4;
  } else if (b < 1280 + cbN){
    int i = (b-1280)*256 + t;
    if (i < N){
      int bb = batch[i];
      int bp = (i > 0) ? batch[i-1] : -1;
      for (int g = bp+1; g <= bb; g++) gstart[g] = i;
      if (i == N-1){
        for (int g = bb+1; g <= G; g++) gstart[g] = N;
      }
    }
  } else if (b == 1280 + cbN){
    for (int i = t; i < NBK_MAX; i += 256) bcur[i] = i * EB_CAP;
  } else if (b < 1280 + cbN + 1 + 32){
    prepW_body(W1, WT1, 64, 128, (b - 1280 - cbN - 1)*256 + t);
  } else {
    prepW_body(W2, WT2, 128, 256, (b - 1280 - cbN - 33)*256 + t);
  }
}

// ---------------- graph preprocessing: 128-node buckets, single-phase passA ----------------
#define PA_TILE 4096

__global__ __launch_bounds__(256) void k_passA(
    const int* __restrict__ row, const int* __restrict__ col,
    int* __restrict__ bcur, uint32_t* __restrict__ ebuf, int E)
{
  __shared__ int hist[NBK_MAX];
  __shared__ int rbase[NBK_MAX];
  int t = threadIdx.x;
  int start = blockIdx.x * PA_TILE;
  for (int i = t; i < NBK_MAX; i += 256) hist[i] = 0;
  __syncthreads();
  uint32_t myv[16]; int myb[16];
  #pragma unroll
  for (int j = 0; j < 16; j++){
    int e = start + t + j*256;
    if (e < E){
      int r = row[e], c = col[e];
      myb[j] = c >> BK_BITS;
      myv[j] = ((uint32_t)r << BK_BITS) | (uint32_t)(c & (BK_SIZE-1));
      atomicAdd(&hist[myb[j]], 1);
    } else myb[j] = -1;
  }
  __syncthreads();
  for (int i = t; i < NBK_MAX; i += 256){
    int h = hist[i];
    rbase[i] = (h > 0) ? atomicAdd(&bcur[i], h) : 0;
  }
  __syncthreads();
  for (int i = t; i < NBK_MAX; i += 256) hist[i] = 0;
  __syncthreads();
  #pragma unroll
  for (int j = 0; j < 16; j++){
    if (myb[j] >= 0){
      int pos = rbase[myb[j]] + atomicAdd(&hist[myb[j]], 1);
      ebuf[pos] = myv[j];
    }
  }
}

// passB2 (128-node buckets) + inlined bucket-prefix scan + fused x->xs conversion
__global__ __launch_bounds__(256) void k_passB2(
    const uint32_t* __restrict__ ebuf, const int* __restrict__ bcur,
    int* __restrict__ offs, float* __restrict__ dinv,
    int* __restrict__ csr,
    const float4* __restrict__ x, ushort4* __restrict__ xs,
    int N, int E, int nb)
{
  __shared__ int deg[BK_SIZE];
  __shared__ int cur[BK_SIZE];
  __shared__ int ps[BK_SIZE];
  __shared__ int red[256];
  int b = blockIdx.x;
  int base = b << BK_BITS;
  int t = threadIdx.x;
  // inline scan: s = sum of counts of buckets < b
  int partial = 0;
  for (int i = t; i < NBK_MAX; i += 256){
    int cnt = bcur[i] - i*EB_CAP;
    if (i < b) partial += cnt;
  }
  red[t] = partial;
  if (t < BK_SIZE) deg[t] = 0;
  __syncthreads();
  for (int off = 128; off > 0; off >>= 1){
    if (t < off) red[t] += red[t+off];
    __syncthreads();
  }
  int s = red[0];
  int ecnt = bcur[b] - b*EB_CAP;
  const uint32_t* eb = ebuf + (size_t)b*EB_CAP;
  for (int i = t; i < ecnt; i += 256)
    atomicAdd(&deg[eb[i] & (BK_SIZE-1u)], 1);
  __syncthreads();
  int d = (t < BK_SIZE) ? deg[t] : 0;
  if (t < BK_SIZE) ps[t] = d;
  __syncthreads();
  for (int off=1; off<BK_SIZE; off<<=1){
    int x_ = 0;
    if (t < BK_SIZE && t >= off) x_ = ps[t-off];
    __syncthreads();
    if (t < BK_SIZE && t >= off) ps[t] += x_;
    __syncthreads();
  }
  if (t < BK_SIZE){
    int o = s + ps[t] - d;
    cur[t] = o;
    int n0 = base + t;
    if (n0 < N){ offs[n0] = o; dinv[n0] = 1.0f / sqrtf((float)(d + 1)); }
  }
  if (b == nb-1 && t == 0) offs[N] = E;
  __syncthreads();
  for (int i = t; i < ecnt; i += 256){
    uint32_t v = eb[i];
    int local = v & (BK_SIZE-1u);
    int pos = atomicAdd(&cur[local], 1);
    csr[pos] = (int)(v >> BK_BITS);
  }
  for (int idx = t; idx < BK_SIZE*16; idx += 256){
    int local = idx >> 4;
    int node = base + local;
    if (node < N){
      float dd = 1.0f / sqrtf((float)(deg[local] + 1));
      int c16 = idx & 15;
      float4 v = x[(size_t)node*16 + c16];
      ushort4 o;
      o.x = f2bf(v.x*dd); o.y = f2bf(v.y*dd); o.z = f2bf(v.z*dd); o.w = f2bf(v.w*dd);
      xs[(size_t)node*16 + c16] = o;
    }
  }
}

// parallel bn finalize: one block per column, slice-parallel tree reduce
__global__ __launch_bounds__(128) void k_bnfin(const float* __restrict__ region, int F, float invCount,
                        const float* __restrict__ g, const float* __restrict__ be,
                        float* __restrict__ scale, float* __restrict__ shift){
  __shared__ float ss[128], sq[128];
  int i  = blockIdx.x;
  int sl = threadIdx.x;
  ss[sl] = region[sl*2*F + i];
  sq[sl] = region[sl*2*F + F + i];
  __syncthreads();
  for (int off = 64; off > 0; off >>= 1){
    if (sl < off){ ss[sl] += ss[sl+off]; sq[sl] += sq[sl+off]; }
    __syncthreads();
  }
  if (sl == 0){
    float mu  = ss[0] * invCount;
    float var = sq[0] * invCount - mu*mu;
    if (var < 0.f) var = 0.f;
    float rstd = 1.0f / sqrtf(var + BN_EPS);
    float sc = g[i] * rstd;
    scale[i] = sc;
    shift[i] = be[i] - mu * sc;
  }
}

// ---------------- aggregation kernels ----------------
__global__ __launch_bounds__(256) void k_agg1(
    const uint4* __restrict__ xs, const int* __restrict__ offs, const int* __restrict__ csr,
    const float* __restrict__ dinv, uint4* __restrict__ z, float* __restrict__ dsum, int N)
{
  int sub = threadIdx.x >> 3, lane = threadIdx.x & 7;
  int node = blockIdx.x*32 + sub;
  if (node >= N) return;
  int s = offs[node], e = offs[node+1];
  float acc[8] = {};
  float ds = 0.f;
  auto add8 = [&](uint4 v){
    float f0,f1,f2,f3,f4,f5,f6,f7;
    bf2f2(v.x, f0, f1); bf2f2(v.y, f2, f3);
    bf2f2(v.z, f4, f5); bf2f2(v.w, f6, f7);
    acc[0]+=f0; acc[1]+=f1; acc[2]+=f2; acc[3]+=f3;
    acc[4]+=f4; acc[5]+=f5; acc[6]+=f6; acc[7]+=f7;
  };
  int i = s;
  for (; i + 4 <= e; i += 4){
    int r0 = csr[i], r1 = csr[i+1], r2 = csr[i+2], r3 = csr[i+3];
    uint4 v0 = xs[r0*8 + lane];
    uint4 v1 = xs[r1*8 + lane];
    uint4 v2 = xs[r2*8 + lane];
    uint4 v3 = xs[r3*8 + lane];
    add8(v0); add8(v1); add8(v2); add8(v3);
    if (lane == 0) ds += dinv[r0] + dinv[r1] + dinv[r2] + dinv[r3];
  }
  for (; i < e; i++){
    int r0 = csr[i];
    add8(xs[r0*8 + lane]);
    if (lane == 0) ds += dinv[r0];
  }
  add8(xs[node*8 + lane]);
  float d = dinv[node];
  if (lane == 0) dsum[node] = ds + d;
  uint4 o;
  o.x = pack2bf(acc[0]*d, acc[1]*d);
  o.y = pack2bf(acc[2]*d, acc[3]*d);
  o.z = pack2bf(acc[4]*d, acc[5]*d);
  o.w = pack2bf(acc[6]*d, acc[7]*d);
  z[(node>>4)*128 + lane*16 + (node&15)] = o;
}

// agg2: gather u (fp8, 16B/lane, 8 lanes/node) -> algebraic bn1 affine -> z2
__global__ __launch_bounds__(256) void k_agg2(
    const uint4* __restrict__ u, const int* __restrict__ offs, const int* __restrict__ csr,
    const float* __restrict__ dinv, const float* __restrict__ dsum,
    const float* __restrict__ sc1, const float* __restrict__ sh1,
    uint4* __restrict__ z, int N)
{
  int sub = threadIdx.x >> 3, lane = threadIdx.x & 7;
  int node = blockIdx.x*32 + sub;
  if (node >= N) return;
  int s = offs[node], e = offs[node+1];
  float acc[16] = {};
  auto add16 = [&](uint4 v){
    f32x2 p;
    p = __builtin_amdgcn_cvt_pk_f32_fp8((int)v.x, false); acc[0]+=p.x;  acc[1]+=p.y;
    p = __builtin_amdgcn_cvt_pk_f32_fp8((int)v.x, true ); acc[2]+=p.x;  acc[3]+=p.y;
    p = __builtin_amdgcn_cvt_pk_f32_fp8((int)v.y, false); acc[4]+=p.x;  acc[5]+=p.y;
    p = __builtin_amdgcn_cvt_pk_f32_fp8((int)v.y, true ); acc[6]+=p.x;  acc[7]+=p.y;
    p = __builtin_amdgcn_cvt_pk_f32_fp8((int)v.z, false); acc[8]+=p.x;  acc[9]+=p.y;
    p = __builtin_amdgcn_cvt_pk_f32_fp8((int)v.z, true ); acc[10]+=p.x; acc[11]+=p.y;
    p = __builtin_amdgcn_cvt_pk_f32_fp8((int)v.w, false); acc[12]+=p.x; acc[13]+=p.y;
    p = __builtin_amdgcn_cvt_pk_f32_fp8((int)v.w, true ); acc[14]+=p.x; acc[15]+=p.y;
  };
  int i = s;
  for (; i + 4 <= e; i += 4){
    int r0 = csr[i], r1 = csr[i+1], r2 = csr[i+2], r3 = csr[i+3];
    uint4 v0 = u[r0*8 + lane];
    uint4 v1 = u[r1*8 + lane];
    uint4 v2 = u[r2*8 + lane];
    uint4 v3 = u[r3*8 + lane];
    add16(v0); add16(v1); add16(v2); add16(v3);
  }
  for (; i < e; i++) add16(u[csr[i]*8 + lane]);
  add16(u[node*8 + lane]);
  float d  = dinv[node];
  float ds = dsum[node];
  int f0 = lane*16;
  uint4 o0, o1;
  {
    float4 sa = *(const float4*)(sc1 + f0);
    float4 sb = *(const float4*)(sc1 + f0 + 4);
    float4 ha = *(const float4*)(sh1 + f0);
    float4 hb = *(const float4*)(sh1 + f0 + 4);
    o0.x = pack2bf(d*fmaf(sa.x, acc[0], ha.x*ds), d*fmaf(sa.y, acc[1], ha.y*ds));
    o0.y = pack2bf(d*fmaf(sa.z, acc[2], ha.z*ds), d*fmaf(sa.w, acc[3], ha.w*ds));
    o0.z = pack2bf(d*fmaf(sb.x, acc[4], hb.x*ds), d*fmaf(sb.y, acc[5], hb.y*ds));
    o0.w = pack2bf(d*fmaf(sb.z, acc[6], hb.z*ds), d*fmaf(sb.w, acc[7], hb.w*ds));
  }
  {
    float4 sa = *(const float4*)(sc1 + f0 + 8);
    float4 sb = *(const float4*)(sc1 + f0 + 12);
    float4 ha = *(const float4*)(sh1 + f0 + 8);
    float4 hb = *(const float4*)(sh1 + f0 + 12);
    o1.x = pack2bf(d*fmaf(sa.x, acc[8],  ha.x*ds), d*fmaf(sa.y, acc[9],  ha.y*ds));
    o1.y = pack2bf(d*fmaf(sa.z, acc[10], ha.z*ds), d*fmaf(sa.w, acc[11], ha.w*ds));
    o1.z = pack2bf(d*fmaf(sb.x, acc[12], hb.x*ds), d*fmaf(sb.y, acc[13], hb.y*ds));
    o1.w = pack2bf(d*fmaf(sb.z, acc[14], hb.z*ds), d*fmaf(sb.w, acc[15], hb.w*ds));
  }
  size_t zb = (size_t)(node>>4)*256 + (node&15);
  z[zb + (2*lane)*16]   = o0;
  z[zb + (2*lane+1)*16] = o1;
}

// ---------------- MFMA node GEMM (CTILE columns per block) ----------------
// POOL: grid (mblk, NOUT/CTILE); per-column pool walk bit-identical to full-width version.
template<int K, int NOUT, int CTILE, bool POOL>
__global__ __launch_bounds__(256) void k_gemm_mfma(
    const uint16_t* __restrict__ A, const uint16_t* __restrict__ WTf,
    const float* __restrict__ bias, const int* __restrict__ batch,
    const float* __restrict__ dinv,
    uint8_t* __restrict__ u_out, float* __restrict__ embsum,
    float* __restrict__ gstats, int N)
{
  constexpr int NT = CTILE/16;
  constexpr int KS = K/32;
  constexpr int TRS8 = CTILE + 16;
  constexpr int TRSF = CTILE + 8;
  __shared__ float s_bias[CTILE];
  __shared__ int s_batch[64];
  __shared__ float s_dinv[POOL ? 1 : 64];
  __shared__ float s_sum[POOL ? 1 : CTILE];
  __shared__ float s_sq[POOL ? 1 : CTILE];
  __shared__ float s_trf[POOL ? 64*TRSF : 1];
  __shared__ uint8_t s_tr8[POOL ? 16 : 64*TRS8];
  int tid = threadIdx.x;
  int w = tid >> 6;
  int lane = tid & 63;
  int l15 = lane & 15, quad = lane >> 4;
  int m0 = blockIdx.x * 64;
  int n0 = blockIdx.y * CTILE;
  int tgbase = n0 >> 4;
  for (int i = tid; i < CTILE; i += 256) s_bias[i] = bias[n0 + i];
  if constexpr (!POOL){
    for (int i = tid; i < CTILE; i += 256){ s_sum[i]=0.f; s_sq[i]=0.f; }
    if (tid < 64) s_dinv[tid] = (m0+tid < N) ? dinv[m0+tid] : 0.f;
  }
  if (POOL && tid < 64) s_batch[tid] = (m0+tid < N) ? batch[m0+tid] : -1;
  __syncthreads();

  const uint16_t* Ag = A + (size_t)(m0/16 + w)*(16*K);

  f32x4 acc[NT];
  #pragma unroll
  for (int t=0;t<NT;t++) acc[t] = (f32x4){0.f,0.f,0.f,0.f};

  #pragma unroll
  for (int ks=0; ks<KS; ks++){
    bf16x8 af = *(const bf16x8*)(Ag + (ks*4 + quad)*128 + l15*8);
    #pragma unroll
    for (int t=0;t<NT;t++){
      bf16x8 bw = *(const bf16x8*)(WTf + (((size_t)((tgbase + t)*KS + ks)*64 + lane) << 3));
      acc[t] = __builtin_amdgcn_mfma_f32_16x16x32_bf16(af, bw, acc[t], 0, 0, 0);
    }
  }

  int rloc = w*16 + quad*4;
  if constexpr (POOL){
    #pragma unroll
    for (int t=0;t<NT;t++){
      int n = t*16 + l15;
      float bv = s_bias[n];
      #pragma unroll
      for (int r=0;r<4;r++){
        bool valid = (m0 + rloc + r) < N;
        float val = fmaxf(acc[t][r] + bv, 0.f);
        s_trf[(rloc + r)*TRSF + n] = valid ? val : 0.f;
      }
    }
    __syncthreads();
    if (tid < CTILE){
      int n = tid;
      float vs = 0.f, vq = 0.f;
      int cur = -1; float run = 0.f;
      #pragma unroll 8
      for (int row = 0; row < 64; row++){
        float v = s_trf[row*TRSF + n];
        vs += v; vq += v*v;
        int b = s_batch[row];
        if (b != cur){
          if (cur >= 0 && run != 0.f) atomicAdd(&embsum[(size_t)cur*NOUT + n0 + n], run);
          cur = b; run = v;
        } else run += v;
      }
      if (cur >= 0 && run != 0.f) atomicAdd(&embsum[(size_t)cur*NOUT + n0 + n], run);
      float* gs = gstats + (size_t)(blockIdx.x & (NSLICE-1))*(2*NOUT);
      atomicAdd(&gs[n0 + n], vs);
      atomicAdd(&gs[NOUT + n0 + n], vq);
    }
  } else {
    #pragma unroll
    for (int t=0;t<NT;t++){
      int n = t*16 + l15;
      float bv = s_bias[n];
      float vs = 0.f, vq = 0.f;
      #pragma unroll
      for (int r=0;r<4;r++){
        bool valid = (m0 + rloc + r) < N;
        float val = fmaxf(acc[t][r] + bv, 0.f);
        float o = valid ? val : 0.f;
        vs += o; vq += o*o;
        s_tr8[(rloc + r)*TRS8 + n] = f2fp8(o * s_dinv[rloc + r]);
      }
      vs += __shfl_xor(vs, 16); vs += __shfl_xor(vs, 32);
      vq += __shfl_xor(vq, 16); vq += __shfl_xor(vq, 32);
      if (quad == 0){
        atomicAdd(&s_sum[n], vs);
        atomicAdd(&s_sq[n], vq);
      }
    }
    __syncthreads();
    constexpr int CPR = CTILE/16;
    for (int i = tid; i < 64*CPR; i += 256){
      int row = i / CPR, c = i - row*CPR;
      int grow = m0 + row;
      if (grow < N)
        *(uint4*)(u_out + (size_t)grow*NOUT + n0 + c*16) = *(const uint4*)(s_tr8 + row*TRS8 + c*16);
    }
    float* gs = gstats + (size_t)(blockIdx.x & (NSLICE-1))*(2*NOUT);
    for (int i = tid; i < CTILE; i += 256){
      atomicAdd(&gs[n0 + i], s_sum[i]);
      atomicAdd(&gs[NOUT + n0 + i], s_sq[i]);
    }
  }
}

// ---------------- GEMM (head MLP, fp32), 32-row x 64-col tiles ----------------
template<int K, int NWTOT, bool CONCAT, bool AFFINE, bool EMB>
__global__ __launch_bounds__(256) void k_gemm_mlp(
    const float* __restrict__ A0, const float* __restrict__ A1,
    const float* __restrict__ W,
    const float* __restrict__ scale, const float* __restrict__ shift,
    const int* __restrict__ gstart, const float* __restrict__ esc, const float* __restrict__ esh,
    const float* __restrict__ bias,
    float* __restrict__ out, float* __restrict__ gstats, int nrows)
{
  __shared__ float As[32*69];
  __shared__ float Bs[32*64];
  __shared__ float s_sum[64], s_sq[64];
  int m0 = blockIdx.x*32;
  int n0 = blockIdx.y*64;
  int tid  = threadIdx.x;
  int tcol = tid & 15, trow = tid >> 4;
  float acc[2][4] = {};
  constexpr int NCH = (K + 31) / 32;
  for (int ch = 0; ch < NCH; ch++){
    int kc0 = ch*32;
    {
      int rr = tid >> 3; int k4 = (tid & 7) << 2;
      int row = m0 + rr;
      int kg = kc0 + k4;
      float4 v = {0.f,0.f,0.f,0.f};
      if (row < nrows){
        if constexpr (CONCAT){
          if (kg < 256){
            v = *(const float4*)(A0 + (size_t)row*256 + kg);
            if constexpr (EMB){
              int c = gstart[row+1] - gstart[row];
              if (c > 0){
                float rinv = 1.0f / (float)c;
                float4 scv = *(const float4*)(esc + kg);
                float4 shv = *(const float4*)(esh + kg);
                v.x = fmaf(v.x*rinv, scv.x, shv.x);
                v.y = fmaf(v.y*rinv, scv.y, shv.y);
                v.z = fmaf(v.z*rinv, scv.z, shv.z);
                v.w = fmaf(v.w*rinv, scv.w, shv.w);
              } else { v.x=v.y=v.z=v.w=0.f; }
            }
          }
          else if (kg < 456) v = *(const float4*)(A1 + (size_t)row*200 + (kg-256));
        } else {
          v = *(const float4*)(A0 + (size_t)row*K + kg);
        }
      }
      if constexpr (AFFINE){
        float4 scv = *(const float4*)(scale + kg);
        float4 shv = *(const float4*)(shift + kg);
        v.x = fmaf(v.x, scv.x, shv.x);
        v.y = fmaf(v.y, scv.y, shv.y);
        v.z = fmaf(v.z, scv.z, shv.z);
        v.w = fmaf(v.w, scv.w, shv.w);
      }
      As[(k4+0)*69 + rr] = v.x;
      As[(k4+1)*69 + rr] = v.y;
      As[(k4+2)*69 + rr] = v.z;
      As[(k4+3)*69 + rr] = v.w;
    }
    #pragma unroll
    for (int j = 0; j < 2; j++){
      int fid = tid + j*256;
      int kk = fid >> 4; int c4 = (fid & 15) << 2;
      int kg = kc0 + kk;
      float4 v = {0.f,0.f,0.f,0.f};
      if (kg < K) v = *(const float4*)(W + (size_t)kg*NWTOT + n0 + c4);
      *(float4*)(Bs + kk*64 + c4) = v;
    }
    __syncthreads();
    #pragma unroll
    for (int kk = 0; kk < 32; kk++){
      float4 b = *(const float4*)(Bs + kk*64 + tcol*4);
      float a0 = As[kk*69 + trow*2];
      float a1 = As[kk*69 + trow*2 + 1];
      acc[0][0] = fmaf(a0, b.x, acc[0][0]);
      acc[0][1] = fmaf(a0, b.y, acc[0][1]);
      acc[0][2] = fmaf(a0, b.z, acc[0][2]);
      acc[0][3] = fmaf(a0, b.w, acc[0][3]);
      acc[1][0] = fmaf(a1, b.x, acc[1][0]);
      acc[1][1] = fmaf(a1, b.y, acc[1][1]);
      acc[1][2] = fmaf(a1, b.z, acc[1][2]);
      acc[1][3] = fmaf(a1, b.w, acc[1][3]);
    }
    __syncthreads();
  }
  if (tid < 64){ s_sum[tid] = 0.f; s_sq[tid] = 0.f; }
  __syncthreads();
  float4 bv = *(const float4*)(bias + n0 + tcol*4);
  float psum[4] = {0,0,0,0}, psq[4] = {0,0,0,0};
  #pragma unroll
  for (int r = 0; r < 2; r++){
    int row = m0 + trow*2 + r;
    if (row < nrows){
      float4 o;
      o.x = fmaxf(acc[r][0] + bv.x, 0.f);
      o.y = fmaxf(acc[r][1] + bv.y, 0.f);
      o.z = fmaxf(acc[r][2] + bv.z, 0.f);
      o.w = fmaxf(acc[r][3] + bv.w, 0.f);
      *(float4*)(out + (size_t)row*NWTOT + n0 + tcol*4) = o;
      psum[0] += o.x; psq[0] += o.x*o.x;
      psum[1] += o.y; psq[1] += o.y*o.y;
      psum[2] += o.z; psq[2] += o.z*o.z;
      psum[3] += o.w; psq[3] += o.w*o.w;
    }
  }
  #pragma unroll
  for (int c = 0; c < 4; c++){
    psum[c] += __shfl_xor(psum[c], 16); psum[c] += __shfl_xor(psum[c], 32);
    psq[c]  += __shfl_xor(psq[c], 16);  psq[c]  += __shfl_xor(psq[c], 32);
  }
  if ((tid & 48) == 0){
    int f0 = tcol*4;
    atomicAdd(&s_sum[f0+0], psum[0]); atomicAdd(&s_sq[f0+0], psq[0]);
    atomicAdd(&s_sum[f0+1], psum[1]); atomicAdd(&s_sq[f0+1], psq[1]);
    atomicAdd(&s_sum[f0+2], psum[2]); atomicAdd(&s_sq[f0+2], psq[2]);
    atomicAdd(&s_sum[f0+3], psum[3]); atomicAdd(&s_sq[f0+3], psq[3]);
  }
  __syncthreads();
  float* gs = gstats + (size_t)(blockIdx.x & (NSLICE-1))*(2*NWTOT);
  if (tid < 64){
    atomicAdd(&gs[n0 + tid], s_sum[tid]);
    atomicAdd(&gs[NWTOT + n0 + tid], s_sq[tid]);
  }
}

// ---------------- final ----------------
__global__ __launch_bounds__(256) void k_final(
    const float* __restrict__ a2, const float* __restrict__ sc, const float* __restrict__ sh,
    const float* __restrict__ w, const float* __restrict__ b, float* __restrict__ out, int G)
{
  int gid  = blockIdx.x*blockDim.x + threadIdx.x;
  int wid  = gid >> 6;
  int lane = gid & 63;
  if (wid >= G) return;
  float2 v = ((const float2*)(a2 + (size_t)wid*128))[lane];
  int k = lane*2;
  float s = fmaf(v.x, sc[k], sh[k]) * w[k] + fmaf(v.y, sc[k+1], sh[k+1]) * w[k+1];
  #pragma unroll
  for (int o = 32; o > 0; o >>= 1) s += __shfl_down(s, o, 64);
  if (lane == 0) out[wid] = s + b[0];
}

// ---------------- launcher ----------------
extern "C" void kernel_launch(void* const* d_in, const int* in_sizes, int n_in,
                              void* d_out, int out_size, void* d_ws, size_t ws_size,
                              hipStream_t stream)
{
  (void)n_in; (void)out_size; (void)ws_size;
  const float* x    = (const float*)d_in[0];
  const int*   ei   = (const int*)d_in[1];
  const int*   batch= (const int*)d_in[2];
  const float* rdk  = (const float*)d_in[3];
  const float* W1   = (const float*)d_in[4];
  const float* b1   = (const float*)d_in[5];
  const float* g1   = (const float*)d_in[6];
  const float* be1  = (const float*)d_in[7];
  const float* W2   = (const float*)d_in[8];
  const float* b2   = (const float*)d_in[9];
  const float* g2   = (const float*)d_in[10];
  const float* be2  = (const float*)d_in[11];
  const float* mW1  = (const float*)d_in[12];
  const float* mb1  = (const float*)d_in[13];
  const float* mg1  = (const float*)d_in[14];
  const float* mbe1 = (const float*)d_in[15];
  const float* mW2  = (const float*)d_in[16];
  const float* mb2  = (const float*)d_in[17];
  const float* mg2  = (const float*)d_in[18];
  const float* mbe2 = (const float*)d_in[19];
  const float* mW3  = (const float*)d_in[20];
  const float* mb3  = (const float*)d_in[21];

  const int N = in_sizes[0] / 64;
  const int E = in_sizes[1] / 2;
  const int G = in_sizes[3] / 200;
  const int* erow = ei;
  const int* ecol = ei + E;
  const int nb = (N + BK_SIZE - 1) >> BK_BITS;

  size_t off = 0;
  auto alloc = [&](size_t bytes)->char*{
    char* p = (char*)d_ws + off;
    off += (bytes + 255) & ~(size_t)255;
    return p;
  };
  int*   offs   = (int*)  alloc(((size_t)N+1)*4);
  int*   csr    = (int*)  alloc((size_t)E*4);
  uint32_t* ebuf= (uint32_t*)alloc((size_t)NBK_MAX*EB_CAP*4);
  int*   bcur   = (int*)  alloc(NBK_MAX*4);
  float* dinv   = (float*)alloc((size_t)N*4);
  float* dsum   = (float*)alloc((size_t)N*4);
  uint16_t* xs  = (uint16_t*)alloc((size_t)N*64*2);
  uint16_t* z1  = (uint16_t*)alloc(((size_t)N+16)*64*2);
  uint8_t*  u   = (uint8_t*)alloc((size_t)N*128);
  uint16_t* z2  = (uint16_t*)alloc(((size_t)N+16)*128*2);
  uint16_t* WT1 = (uint16_t*)alloc((size_t)128*64*2);
  uint16_t* WT2 = (uint16_t*)alloc((size_t)256*128*2);
  float* embsum = (float*)alloc((size_t)G*256*4);
  int*   gstart = (int*)  alloc(((size_t)G+1)*4);
  float* a1     = (float*)alloc((size_t)G*256*4);
  float* a2     = (float*)alloc((size_t)G*128*4);
  float* gstats = (float*)alloc((size_t)4*NSLICE*2*256*4);
  float* scsh   = (float*)alloc((size_t)4*2*256*4);

  float* gs0 = gstats;
  float* gs1 = gstats + NSLICE*2*256;
  float* gs2 = gstats + 2*NSLICE*2*256;
  float* gs3 = gstats + 3*NSLICE*2*256;
  float* sc1 = scsh;        float* sh1 = scsh + 256;
  float* sc2 = scsh + 512;  float* sh2 = scsh + 768;
  float* sc3 = scsh + 1024; float* sh3 = scsh + 1280;
  float* sc4 = scsh + 1536; float* sh4 = scsh + 1792;

  int cbN   = (N + 255) / 256;
  int mblk  = (N + 63) / 64;
  int gblk32= (G + 31) / 32;
  int ablk  = (E + PA_TILE - 1) / PA_TILE;

  k_misc<<<1280 + cbN + 1 + 32 + 128, 256, 0, stream>>>(
      batch, gstart, N, G, cbN, W1, WT1, W2, WT2, bcur,
      (float4*)gstats, (float4*)embsum);

  k_passA<<<ablk,256,0,stream>>>(erow, ecol, bcur, ebuf, E);
  k_passB2<<<nb,256,0,stream>>>(ebuf, bcur, offs, dinv, csr, (const float4*)x, (ushort4*)xs, N, E, nb);

  k_agg1<<<(N+31)/32,256,0,stream>>>((const uint4*)xs, offs, csr, dinv, (uint4*)z1, dsum, N);
  k_gemm_mfma<64,128,128,false><<<dim3(mblk,1),256,0,stream>>>(z1, WT1, b1, nullptr, dinv, u, nullptr, gs0, N);
  k_bnfin<<<128,128,0,stream>>>(gs0, 128, 1.0f/(float)N, g1, be1, sc1, sh1);

  k_agg2<<<(N+31)/32,256,0,stream>>>((const uint4*)u, offs, csr, dinv, dsum, sc1, sh1, (uint4*)z2, N);
  k_gemm_mfma<128,256,128,true><<<dim3(mblk,2),256,0,stream>>>(z2, WT2, b2, batch, nullptr, nullptr, embsum, gs1, N);
  k_bnfin<<<256,128,0,stream>>>(gs1, 256, 1.0f/(float)N, g2, be2, sc2, sh2);

  k_gemm_mlp<456,256,true,false,true><<<dim3(gblk32,4),256,0,stream>>>(embsum, rdk, mW1, nullptr, nullptr, gstart, sc2, sh2, mb1, a1, gs2, G);
  k_bnfin<<<256,128,0,stream>>>(gs2, 256, 1.0f/(float)G, mg1, mbe1, sc3, sh3);
  k_gemm_mlp<256,128,false,true,false><<<dim3(gblk32,2),256,0,stream>>>(a1, nullptr, mW2, sc3, sh3, nullptr, nullptr, nullptr, mb2, a2, gs3, G);
  k_bnfin<<<128,128,0,stream>>>(gs3, 128, 1.0f/(float)G, mg2, mbe2, sc4, sh4);
  k_final<<<(G+3)/4,256,0,stream>>>(a2, sc4, sh4, mW3, mb3, (float*)d_out, G);
}